// Round 1
// baseline (1679.808 us; speedup 1.0000x reference)
//
#include <hip/hip_runtime.h>
#include <math.h>

// ---------------------------------------------------------------------------
// GCN anomaly detector, fp32 throughout.
// Pipeline:
//   1. detect edge_index dtype (int32 vs int64) on device
//   2. deg histogram (atomics) -> dis = rsqrt(deg+1)
//   3. exclusive scan -> CSR row offsets; scatter edges into CSR (by dst)
//   4. hw1 = x @ W1            (GEMM 128->64)
//   5. h1  = relu(agg1 + b1)   (pull-gather per node, wave=node, lane=feat)
//   6. hw2 = h1 @ W2           (GEMM 64->32)
//   7. h   = agg2 + b2         -> d_out[0 : N*32]
//   8. t   = relu(h@rW1+rb1)   (GEMM 32->64)
//   9. xr  = t@rW2+rb2         (GEMM 64->128) -> d_out[N*32 : N*32+N*128]
//  10. s   = relu(h@sW1+sb1)   (GEMM 32->32)
//  11. score = sigmoid(s@sW2+sb2) -> d_out[N*32+N*128 : ]
// ---------------------------------------------------------------------------

__global__ void k_detect(const unsigned int* __restrict__ w, int npairs,
                         int* __restrict__ meta) {
  __shared__ int any;
  if (threadIdx.x == 0) any = 0;
  __syncthreads();
  int local = 0;
  for (int i = threadIdx.x; i < npairs; i += blockDim.x)
    local |= (w[2 * i + 1] != 0u);
  if (local) atomicOr(&any, 1);
  __syncthreads();
  if (threadIdx.x == 0) meta[0] = any ? 0 : 1;  // 1 => edge_index is int64
}

__global__ void k_hist(const void* __restrict__ ei, int E,
                       int* __restrict__ cnt, const int* __restrict__ meta) {
  int e = blockIdx.x * blockDim.x + threadIdx.x;
  if (e >= E) return;
  int d;
  if (meta[0]) d = (int)((const long long*)ei)[(long)E + e];
  else         d = ((const int*)ei)[(long)E + e];
  atomicAdd(&cnt[d], 1);
}

__global__ void k_dis(const int* __restrict__ cnt, float* __restrict__ dis, int n) {
  int i = blockIdx.x * blockDim.x + threadIdx.x;
  if (i < n) dis[i] = rsqrtf((float)cnt[i] + 1.0f);
}

__global__ __launch_bounds__(1024) void k_scan1(const int* __restrict__ cnt,
                                                int* __restrict__ bsums, int n) {
  __shared__ int sm[1024];
  int t = threadIdx.x;
  long i = (long)blockIdx.x * 1024 + t;
  sm[t] = (i < n) ? cnt[i] : 0;
  __syncthreads();
  for (int s = 512; s > 0; s >>= 1) {
    if (t < s) sm[t] += sm[t + s];
    __syncthreads();
  }
  if (t == 0) bsums[blockIdx.x] = sm[0];
}

__global__ void k_scan2(int* __restrict__ bsums, int nb) {
  __shared__ int sm[128];
  int t = threadIdx.x;
  int v = (t < nb) ? bsums[t] : 0;
  sm[t] = v;
  __syncthreads();
  for (int off = 1; off < 128; off <<= 1) {
    int x = (t >= off) ? sm[t - off] : 0;
    __syncthreads();
    sm[t] += x;
    __syncthreads();
  }
  if (t < nb) bsums[t] = sm[t] - v;  // exclusive
}

__global__ __launch_bounds__(1024) void k_scan3(const int* __restrict__ cnt,
                                                const int* __restrict__ bsums,
                                                int* __restrict__ rs,
                                                int* __restrict__ cursor, int n) {
  __shared__ int sm[1024];
  int t = threadIdx.x;
  long i = (long)blockIdx.x * 1024 + t;
  int v = (i < n) ? cnt[i] : 0;
  sm[t] = v;
  __syncthreads();
  for (int off = 1; off < 1024; off <<= 1) {
    int x = (t >= off) ? sm[t - off] : 0;
    __syncthreads();
    sm[t] += x;
    __syncthreads();
  }
  int excl = sm[t] - v + bsums[blockIdx.x];
  if (i < n) { rs[i] = excl; cursor[i] = excl; }
}

__global__ void k_scatter(const void* __restrict__ ei, int E,
                          int* __restrict__ cursor, int* __restrict__ csr,
                          const int* __restrict__ meta) {
  int e = blockIdx.x * blockDim.x + threadIdx.x;
  if (e >= E) return;
  int s, d;
  if (meta[0]) {
    const long long* p = (const long long*)ei;
    s = (int)p[e]; d = (int)p[(long)E + e];
  } else {
    const int* p = (const int*)ei;
    s = p[e]; d = p[(long)E + e];
  }
  int pos = atomicAdd(&cursor[d], 1);
  csr[pos] = s;
}

// C[n, M] = act(A[n, K] @ W[K, M] (+ bias)); W row-major [K][M], staged in LDS.
// 256 threads; each thread: RP=4 rows x CP=4 cols.
template <int K, int M, bool BIAS, int ACT>
__global__ __launch_bounds__(256) void k_gemm(const float* __restrict__ A,
                                              const float* __restrict__ W,
                                              const float* __restrict__ bias,
                                              float* __restrict__ C, int nrows) {
  constexpr int CP = 4;
  constexpr int TPR = M / CP;        // threads per row
  constexpr int RG = 256 / TPR;      // row-groups per block
  constexpr int RP = 4;              // rows per thread
  constexpr int RT = RG * RP;        // rows per block
  __shared__ __align__(16) float sW[K * M];
  __shared__ __align__(16) float sB[M];

  for (int i = threadIdx.x; i < K * M / 4; i += 256)
    ((float4*)sW)[i] = ((const float4*)W)[i];
  if (BIAS)
    for (int i = threadIdx.x; i < M; i += 256) sB[i] = bias[i];
  __syncthreads();

  const int cg = threadIdx.x % TPR;
  const int rg = threadIdx.x / TPR;
  const long row0 = (long)blockIdx.x * RT + rg;

  float acc[RP][CP] = {};
  for (int k0 = 0; k0 < K; k0 += 4) {
    float4 a[RP];
#pragma unroll
    for (int r = 0; r < RP; ++r) {
      long row = row0 + (long)r * RG;
      a[r] = (row < nrows) ? ((const float4*)(A + row * K))[k0 / 4]
                           : make_float4(0.f, 0.f, 0.f, 0.f);
    }
#pragma unroll
    for (int j = 0; j < 4; ++j) {
      float4 w = ((const float4*)(sW + (k0 + j) * M))[cg];
#pragma unroll
      for (int r = 0; r < RP; ++r) {
        float av = (j == 0) ? a[r].x : (j == 1) ? a[r].y : (j == 2) ? a[r].z : a[r].w;
        acc[r][0] += av * w.x;
        acc[r][1] += av * w.y;
        acc[r][2] += av * w.z;
        acc[r][3] += av * w.w;
      }
    }
  }
#pragma unroll
  for (int r = 0; r < RP; ++r) {
    long row = row0 + (long)r * RG;
    if (row >= nrows) continue;
    float4 o = make_float4(acc[r][0], acc[r][1], acc[r][2], acc[r][3]);
    if (BIAS) {
      float4 bb = ((const float4*)sB)[cg];
      o.x += bb.x; o.y += bb.y; o.z += bb.z; o.w += bb.w;
    }
    if (ACT == 1) {
      o.x = fmaxf(o.x, 0.f); o.y = fmaxf(o.y, 0.f);
      o.z = fmaxf(o.z, 0.f); o.w = fmaxf(o.w, 0.f);
    }
    ((float4*)(C + row * M))[cg] = o;
  }
}

// Pull aggregation, D=64 features: one wave per node, lane = feature.
__global__ __launch_bounds__(256) void k_agg64(const float* __restrict__ hw,
                                               const int* __restrict__ csr,
                                               const int* __restrict__ rs,
                                               const int* __restrict__ cnt,
                                               const float* __restrict__ dis,
                                               const float* __restrict__ b,
                                               float* __restrict__ out, int n,
                                               int relu) {
  int node = blockIdx.x * 4 + (threadIdx.x >> 6);
  if (node >= n) return;
  int f = threadIdx.x & 63;
  float dsn = dis[node];
  float acc = hw[(long)node * 64 + f] * dsn * dsn;  // self-loop
  int start = rs[node], deg = cnt[node];
  int e = 0;
  for (; e + 1 < deg; e += 2) {
    int s0 = csr[start + e];
    int s1 = csr[start + e + 1];
    float n0 = dis[s0] * dsn;
    float n1 = dis[s1] * dsn;
    acc += hw[(long)s0 * 64 + f] * n0;
    acc += hw[(long)s1 * 64 + f] * n1;
  }
  if (e < deg) {
    int s0 = csr[start + e];
    acc += hw[(long)s0 * 64 + f] * (dis[s0] * dsn);
  }
  float o = acc + b[f];
  out[(long)node * 64 + f] = relu ? fmaxf(o, 0.f) : o;
}

// Pull aggregation, D=32 features: two nodes per wave.
__global__ __launch_bounds__(256) void k_agg32(const float* __restrict__ hw,
                                               const int* __restrict__ csr,
                                               const int* __restrict__ rs,
                                               const int* __restrict__ cnt,
                                               const float* __restrict__ dis,
                                               const float* __restrict__ b,
                                               float* __restrict__ out, int n) {
  int node = blockIdx.x * 8 + (threadIdx.x >> 5);
  if (node >= n) return;
  int f = threadIdx.x & 31;
  float dsn = dis[node];
  float acc = hw[(long)node * 32 + f] * dsn * dsn;
  int start = rs[node], deg = cnt[node];
  int e = 0;
  for (; e + 1 < deg; e += 2) {
    int s0 = csr[start + e];
    int s1 = csr[start + e + 1];
    float n0 = dis[s0] * dsn;
    float n1 = dis[s1] * dsn;
    acc += hw[(long)s0 * 32 + f] * n0;
    acc += hw[(long)s1 * 32 + f] * n1;
  }
  if (e < deg) {
    int s0 = csr[start + e];
    acc += hw[(long)s0 * 32 + f] * (dis[s0] * dsn);
  }
  out[(long)node * 32 + f] = acc + b[f];
}

// score = sigmoid(s[N,32] @ sW2[32] + sb2); 8 nodes per 256-thread block.
__global__ void k_score(const float* __restrict__ s, const float* __restrict__ sW2,
                        const float* __restrict__ sb2, float* __restrict__ out, int n) {
  int node = blockIdx.x * 8 + (threadIdx.x >> 5);
  int k = threadIdx.x & 31;
  if (node >= n) return;
  float v = s[(long)node * 32 + k] * sW2[k];
  for (int off = 16; off > 0; off >>= 1) v += __shfl_down(v, off, 32);
  if (k == 0) out[node] = 1.0f / (1.0f + expf(-(v + sb2[0])));
}

extern "C" void kernel_launch(void* const* d_in, const int* in_sizes, int n_in,
                              void* d_out, int out_size, void* d_ws, size_t ws_size,
                              hipStream_t stream) {
  const float* x   = (const float*)d_in[0];
  const void*  ei  = d_in[1];
  const float* W1  = (const float*)d_in[2];
  const float* b1  = (const float*)d_in[3];
  const float* W2  = (const float*)d_in[4];
  const float* b2  = (const float*)d_in[5];
  const float* rW1 = (const float*)d_in[6];
  const float* rb1 = (const float*)d_in[7];
  const float* rW2 = (const float*)d_in[8];
  const float* rb2 = (const float*)d_in[9];
  const float* sW1 = (const float*)d_in[10];
  const float* sb1 = (const float*)d_in[11];
  const float* sW2 = (const float*)d_in[12];
  const float* sb2 = (const float*)d_in[13];

  const int N = in_sizes[0] / 128;
  const int E = in_sizes[1] / 2;

  // workspace layout (256B aligned chunks)
  char* w = (char*)d_ws;
  auto alloc = [&](size_t bytes) {
    char* p = w;
    w += (bytes + 255) & ~(size_t)255;
    return p;
  };
  int*   meta   = (int*)alloc(64);
  int*   cnt    = (int*)alloc((size_t)N * 4);
  int*   rs     = (int*)alloc((size_t)N * 4);
  int*   cursor = (int*)alloc((size_t)N * 4);
  float* dis    = (float*)alloc((size_t)N * 4);
  int*   bsums  = (int*)alloc(1024);
  int*   csr    = (int*)alloc((size_t)E * 4);
  float* hw1    = (float*)alloc((size_t)N * 64 * 4);  // also reused as t
  float* h1     = (float*)alloc((size_t)N * 64 * 4);
  float* hw2    = (float*)alloc((size_t)N * 32 * 4);  // also reused as s

  float* h_out = (float*)d_out;                 // [N,32]
  float* x_rec = h_out + (long)N * 32;          // [N,128]
  float* score = x_rec + (long)N * 128;         // [N,1]

  hipMemsetAsync(cnt, 0, (size_t)N * 4, stream);
  k_detect<<<1, 256, 0, stream>>>((const unsigned int*)ei, 4096, meta);
  k_hist<<<(E + 255) / 256, 256, 0, stream>>>(ei, E, cnt, meta);
  k_dis<<<(N + 255) / 256, 256, 0, stream>>>(cnt, dis, N);

  int nb1 = (N + 1023) / 1024;
  k_scan1<<<nb1, 1024, 0, stream>>>(cnt, bsums, N);
  k_scan2<<<1, 128, 0, stream>>>(bsums, nb1);
  k_scan3<<<nb1, 1024, 0, stream>>>(cnt, bsums, rs, cursor, N);
  k_scatter<<<(E + 255) / 256, 256, 0, stream>>>(ei, E, cursor, csr, meta);

  // layer 1: hw1 = x @ W1 ; h1 = relu(agg + b1)
  k_gemm<128, 64, false, 0><<<(N + 63) / 64, 256, 0, stream>>>(x, W1, nullptr, hw1, N);
  k_agg64<<<(N + 3) / 4, 256, 0, stream>>>(hw1, csr, rs, cnt, dis, b1, h1, N, 1);

  // layer 2: hw2 = h1 @ W2 ; h = agg + b2  -> d_out
  k_gemm<64, 32, false, 0><<<(N + 127) / 128, 256, 0, stream>>>(h1, W2, nullptr, hw2, N);
  k_agg32<<<(N + 7) / 8, 256, 0, stream>>>(hw2, csr, rs, cnt, dis, b2, h_out, N);

  // reconstruction MLP: t = relu(h@rW1+rb1) ; x_rec = t@rW2+rb2
  float* tbuf = hw1;
  k_gemm<32, 64, true, 1><<<(N + 63) / 64, 256, 0, stream>>>(h_out, rW1, rb1, tbuf, N);
  k_gemm<64, 128, true, 0><<<(N + 31) / 32, 256, 0, stream>>>(tbuf, rW2, rb2, x_rec, N);

  // scorer MLP: s = relu(h@sW1+sb1) ; score = sigmoid(s@sW2+sb2)
  float* sbuf = hw2;
  k_gemm<32, 32, true, 1><<<(N + 127) / 128, 256, 0, stream>>>(h_out, sW1, sb1, sbuf, N);
  k_score<<<(N + 7) / 8, 256, 0, stream>>>(sbuf, sW2, sb2, score, N);
}

// Round 2
// 807.818 us; speedup vs baseline: 2.0794x; 2.0794x over previous
//
#include <hip/hip_runtime.h>
#include <math.h>

// ---------------------------------------------------------------------------
// GCN anomaly detector, fp32 throughout.
// Round 1 fix: k_gemm's K-loop was fully unrolled by the compiler, hoisting
// up to 512 A-registers -> VGPR=256 + massive scratch spill (2.1 GB HBM
// traffic, 843us on the 128->64 GEMM alone). Now: #pragma unroll 1 with a
// manual 1-deep prefetch pipeline (32 live A regs).
// ---------------------------------------------------------------------------

__global__ void k_detect(const unsigned int* __restrict__ w, int npairs,
                         int* __restrict__ meta) {
  __shared__ int any;
  if (threadIdx.x == 0) any = 0;
  __syncthreads();
  int local = 0;
  for (int i = threadIdx.x; i < npairs; i += blockDim.x)
    local |= (w[2 * i + 1] != 0u);
  if (local) atomicOr(&any, 1);
  __syncthreads();
  if (threadIdx.x == 0) meta[0] = any ? 0 : 1;  // 1 => edge_index is int64
}

__global__ void k_hist(const void* __restrict__ ei, int E,
                       int* __restrict__ cnt, const int* __restrict__ meta) {
  int e = blockIdx.x * blockDim.x + threadIdx.x;
  if (e >= E) return;
  int d;
  if (meta[0]) d = (int)((const long long*)ei)[(long)E + e];
  else         d = ((const int*)ei)[(long)E + e];
  atomicAdd(&cnt[d], 1);
}

__global__ void k_dis(const int* __restrict__ cnt, float* __restrict__ dis, int n) {
  int i = blockIdx.x * blockDim.x + threadIdx.x;
  if (i < n) dis[i] = rsqrtf((float)cnt[i] + 1.0f);
}

__global__ __launch_bounds__(1024) void k_scan1(const int* __restrict__ cnt,
                                                int* __restrict__ bsums, int n) {
  __shared__ int sm[1024];
  int t = threadIdx.x;
  long i = (long)blockIdx.x * 1024 + t;
  sm[t] = (i < n) ? cnt[i] : 0;
  __syncthreads();
  for (int s = 512; s > 0; s >>= 1) {
    if (t < s) sm[t] += sm[t + s];
    __syncthreads();
  }
  if (t == 0) bsums[blockIdx.x] = sm[0];
}

__global__ void k_scan2(int* __restrict__ bsums, int nb) {
  __shared__ int sm[128];
  int t = threadIdx.x;
  int v = (t < nb) ? bsums[t] : 0;
  sm[t] = v;
  __syncthreads();
  for (int off = 1; off < 128; off <<= 1) {
    int x = (t >= off) ? sm[t - off] : 0;
    __syncthreads();
    sm[t] += x;
    __syncthreads();
  }
  if (t < nb) bsums[t] = sm[t] - v;  // exclusive
}

__global__ __launch_bounds__(1024) void k_scan3(const int* __restrict__ cnt,
                                                const int* __restrict__ bsums,
                                                int* __restrict__ rs,
                                                int* __restrict__ cursor, int n) {
  __shared__ int sm[1024];
  int t = threadIdx.x;
  long i = (long)blockIdx.x * 1024 + t;
  int v = (i < n) ? cnt[i] : 0;
  sm[t] = v;
  __syncthreads();
  for (int off = 1; off < 1024; off <<= 1) {
    int x = (t >= off) ? sm[t - off] : 0;
    __syncthreads();
    sm[t] += x;
    __syncthreads();
  }
  int excl = sm[t] - v + bsums[blockIdx.x];
  if (i < n) { rs[i] = excl; cursor[i] = excl; }
}

__global__ void k_scatter(const void* __restrict__ ei, int E,
                          int* __restrict__ cursor, int* __restrict__ csr,
                          const int* __restrict__ meta) {
  int e = blockIdx.x * blockDim.x + threadIdx.x;
  if (e >= E) return;
  int s, d;
  if (meta[0]) {
    const long long* p = (const long long*)ei;
    s = (int)p[e]; d = (int)p[(long)E + e];
  } else {
    const int* p = (const int*)ei;
    s = p[e]; d = p[(long)E + e];
  }
  int pos = atomicAdd(&cursor[d], 1);
  csr[pos] = s;
}

// C[n, M] = act(A[n, K] @ W[K, M] (+ bias)); W row-major [K][M], staged in LDS.
// 256 threads; each thread: RP=4 rows x CP=4 cols.
// K-loop pinned to no-unroll + manual next-k prefetch: 32 live A regs, no spill.
template <int K, int M, bool BIAS, int ACT>
__global__ __launch_bounds__(256) void k_gemm(const float* __restrict__ A,
                                              const float* __restrict__ W,
                                              const float* __restrict__ bias,
                                              float* __restrict__ C, int nrows) {
  constexpr int CP = 4;
  constexpr int TPR = M / CP;        // threads per row
  constexpr int RG = 256 / TPR;      // row-groups per block
  constexpr int RP = 4;              // rows per thread
  constexpr int RT = RG * RP;        // rows per block
  __shared__ __align__(16) float sW[K * M];
  __shared__ __align__(16) float sB[BIAS ? M : 4];

  for (int i = threadIdx.x; i < K * M / 4; i += 256)
    ((float4*)sW)[i] = ((const float4*)W)[i];
  if (BIAS)
    for (int i = threadIdx.x; i < M; i += 256) sB[i] = bias[i];
  __syncthreads();

  const int cg = threadIdx.x % TPR;
  const int rg = threadIdx.x / TPR;
  const long row0 = (long)blockIdx.x * RT + rg;

  const float4* Ap[RP];
  bool valid[RP];
#pragma unroll
  for (int r = 0; r < RP; ++r) {
    long row = row0 + (long)r * RG;
    valid[r] = (row < nrows);
    Ap[r] = (const float4*)(A + (valid[r] ? row : 0) * K);
  }

  float acc[RP][CP] = {};
  float4 a[RP];
#pragma unroll
  for (int r = 0; r < RP; ++r)
    a[r] = valid[r] ? Ap[r][0] : make_float4(0.f, 0.f, 0.f, 0.f);

#pragma unroll 1
  for (int k0 = 0; k0 < K - 4; k0 += 4) {
    float4 an[RP];
#pragma unroll
    for (int r = 0; r < RP; ++r)
      an[r] = valid[r] ? Ap[r][k0 / 4 + 1] : make_float4(0.f, 0.f, 0.f, 0.f);
#pragma unroll
    for (int j = 0; j < 4; ++j) {
      float4 w = ((const float4*)(sW + (k0 + j) * M))[cg];
#pragma unroll
      for (int r = 0; r < RP; ++r) {
        float av = (j == 0) ? a[r].x : (j == 1) ? a[r].y : (j == 2) ? a[r].z : a[r].w;
        acc[r][0] += av * w.x;
        acc[r][1] += av * w.y;
        acc[r][2] += av * w.z;
        acc[r][3] += av * w.w;
      }
    }
#pragma unroll
    for (int r = 0; r < RP; ++r) a[r] = an[r];
  }
  {  // last k-step
    const int k0 = K - 4;
#pragma unroll
    for (int j = 0; j < 4; ++j) {
      float4 w = ((const float4*)(sW + (k0 + j) * M))[cg];
#pragma unroll
      for (int r = 0; r < RP; ++r) {
        float av = (j == 0) ? a[r].x : (j == 1) ? a[r].y : (j == 2) ? a[r].z : a[r].w;
        acc[r][0] += av * w.x;
        acc[r][1] += av * w.y;
        acc[r][2] += av * w.z;
        acc[r][3] += av * w.w;
      }
    }
  }

#pragma unroll
  for (int r = 0; r < RP; ++r) {
    long row = row0 + (long)r * RG;
    if (row >= nrows) continue;
    float4 o = make_float4(acc[r][0], acc[r][1], acc[r][2], acc[r][3]);
    if (BIAS) {
      float4 bb = ((const float4*)sB)[cg];
      o.x += bb.x; o.y += bb.y; o.z += bb.z; o.w += bb.w;
    }
    if (ACT == 1) {
      o.x = fmaxf(o.x, 0.f); o.y = fmaxf(o.y, 0.f);
      o.z = fmaxf(o.z, 0.f); o.w = fmaxf(o.w, 0.f);
    }
    ((float4*)(C + row * M))[cg] = o;
  }
}

// Pull aggregation, D=64 features: one wave per node, lane = feature.
__global__ __launch_bounds__(256) void k_agg64(const float* __restrict__ hw,
                                               const int* __restrict__ csr,
                                               const int* __restrict__ rs,
                                               const int* __restrict__ cnt,
                                               const float* __restrict__ dis,
                                               const float* __restrict__ b,
                                               float* __restrict__ out, int n,
                                               int relu) {
  int node = blockIdx.x * 4 + (threadIdx.x >> 6);
  if (node >= n) return;
  int f = threadIdx.x & 63;
  float dsn = dis[node];
  float acc = hw[(long)node * 64 + f] * dsn * dsn;  // self-loop
  int start = rs[node], deg = cnt[node];
  int e = 0;
  for (; e + 1 < deg; e += 2) {
    int s0 = csr[start + e];
    int s1 = csr[start + e + 1];
    float n0 = dis[s0] * dsn;
    float n1 = dis[s1] * dsn;
    acc += hw[(long)s0 * 64 + f] * n0;
    acc += hw[(long)s1 * 64 + f] * n1;
  }
  if (e < deg) {
    int s0 = csr[start + e];
    acc += hw[(long)s0 * 64 + f] * (dis[s0] * dsn);
  }
  float o = acc + b[f];
  out[(long)node * 64 + f] = relu ? fmaxf(o, 0.f) : o;
}

// Pull aggregation, D=32 features: two nodes per wave.
__global__ __launch_bounds__(256) void k_agg32(const float* __restrict__ hw,
                                               const int* __restrict__ csr,
                                               const int* __restrict__ rs,
                                               const int* __restrict__ cnt,
                                               const float* __restrict__ dis,
                                               const float* __restrict__ b,
                                               float* __restrict__ out, int n) {
  int node = blockIdx.x * 8 + (threadIdx.x >> 5);
  if (node >= n) return;
  int f = threadIdx.x & 31;
  float dsn = dis[node];
  float acc = hw[(long)node * 32 + f] * dsn * dsn;
  int start = rs[node], deg = cnt[node];
  int e = 0;
  for (; e + 1 < deg; e += 2) {
    int s0 = csr[start + e];
    int s1 = csr[start + e + 1];
    float n0 = dis[s0] * dsn;
    float n1 = dis[s1] * dsn;
    acc += hw[(long)s0 * 32 + f] * n0;
    acc += hw[(long)s1 * 32 + f] * n1;
  }
  if (e < deg) {
    int s0 = csr[start + e];
    acc += hw[(long)s0 * 32 + f] * (dis[s0] * dsn);
  }
  out[(long)node * 32 + f] = acc + b[f];
}

// score = sigmoid(s[N,32] @ sW2[32] + sb2); 8 nodes per 256-thread block.
__global__ void k_score(const float* __restrict__ s, const float* __restrict__ sW2,
                        const float* __restrict__ sb2, float* __restrict__ out, int n) {
  int node = blockIdx.x * 8 + (threadIdx.x >> 5);
  int k = threadIdx.x & 31;
  if (node >= n) return;
  float v = s[(long)node * 32 + k] * sW2[k];
  for (int off = 16; off > 0; off >>= 1) v += __shfl_down(v, off, 32);
  if (k == 0) out[node] = 1.0f / (1.0f + expf(-(v + sb2[0])));
}

extern "C" void kernel_launch(void* const* d_in, const int* in_sizes, int n_in,
                              void* d_out, int out_size, void* d_ws, size_t ws_size,
                              hipStream_t stream) {
  const float* x   = (const float*)d_in[0];
  const void*  ei  = d_in[1];
  const float* W1  = (const float*)d_in[2];
  const float* b1  = (const float*)d_in[3];
  const float* W2  = (const float*)d_in[4];
  const float* b2  = (const float*)d_in[5];
  const float* rW1 = (const float*)d_in[6];
  const float* rb1 = (const float*)d_in[7];
  const float* rW2 = (const float*)d_in[8];
  const float* rb2 = (const float*)d_in[9];
  const float* sW1 = (const float*)d_in[10];
  const float* sb1 = (const float*)d_in[11];
  const float* sW2 = (const float*)d_in[12];
  const float* sb2 = (const float*)d_in[13];

  const int N = in_sizes[0] / 128;
  const int E = in_sizes[1] / 2;

  // workspace layout (256B aligned chunks)
  char* w = (char*)d_ws;
  auto alloc = [&](size_t bytes) {
    char* p = w;
    w += (bytes + 255) & ~(size_t)255;
    return p;
  };
  int*   meta   = (int*)alloc(64);
  int*   cnt    = (int*)alloc((size_t)N * 4);
  int*   rs     = (int*)alloc((size_t)N * 4);
  int*   cursor = (int*)alloc((size_t)N * 4);
  float* dis    = (float*)alloc((size_t)N * 4);
  int*   bsums  = (int*)alloc(1024);
  int*   csr    = (int*)alloc((size_t)E * 4);
  float* hw1    = (float*)alloc((size_t)N * 64 * 4);  // also reused as t
  float* h1     = (float*)alloc((size_t)N * 64 * 4);
  float* hw2    = (float*)alloc((size_t)N * 32 * 4);  // also reused as s

  float* h_out = (float*)d_out;                 // [N,32]
  float* x_rec = h_out + (long)N * 32;          // [N,128]
  float* score = x_rec + (long)N * 128;         // [N,1]

  hipMemsetAsync(cnt, 0, (size_t)N * 4, stream);
  k_detect<<<1, 256, 0, stream>>>((const unsigned int*)ei, 4096, meta);
  k_hist<<<(E + 255) / 256, 256, 0, stream>>>(ei, E, cnt, meta);
  k_dis<<<(N + 255) / 256, 256, 0, stream>>>(cnt, dis, N);

  int nb1 = (N + 1023) / 1024;
  k_scan1<<<nb1, 1024, 0, stream>>>(cnt, bsums, N);
  k_scan2<<<1, 128, 0, stream>>>(bsums, nb1);
  k_scan3<<<nb1, 1024, 0, stream>>>(cnt, bsums, rs, cursor, N);
  k_scatter<<<(E + 255) / 256, 256, 0, stream>>>(ei, E, cursor, csr, meta);

  // layer 1: hw1 = x @ W1 ; h1 = relu(agg + b1)
  k_gemm<128, 64, false, 0><<<(N + 63) / 64, 256, 0, stream>>>(x, W1, nullptr, hw1, N);
  k_agg64<<<(N + 3) / 4, 256, 0, stream>>>(hw1, csr, rs, cnt, dis, b1, h1, N, 1);

  // layer 2: hw2 = h1 @ W2 ; h = agg + b2  -> d_out
  k_gemm<64, 32, false, 0><<<(N + 127) / 128, 256, 0, stream>>>(h1, W2, nullptr, hw2, N);
  k_agg32<<<(N + 7) / 8, 256, 0, stream>>>(hw2, csr, rs, cnt, dis, b2, h_out, N);

  // reconstruction MLP: t = relu(h@rW1+rb1) ; x_rec = t@rW2+rb2
  float* tbuf = hw1;
  k_gemm<32, 64, true, 1><<<(N + 63) / 64, 256, 0, stream>>>(h_out, rW1, rb1, tbuf, N);
  k_gemm<64, 128, true, 0><<<(N + 31) / 32, 256, 0, stream>>>(tbuf, rW2, rb2, x_rec, N);

  // scorer MLP: s = relu(h@sW1+sb1) ; score = sigmoid(s@sW2+sb2)
  float* sbuf = hw2;
  k_gemm<32, 32, true, 1><<<(N + 127) / 128, 256, 0, stream>>>(h_out, sW1, sb1, sbuf, N);
  k_score<<<(N + 7) / 8, 256, 0, stream>>>(sbuf, sW2, sb2, score, N);
}

// Round 3
// 570.088 us; speedup vs baseline: 2.9466x; 1.4170x over previous
//
#include <hip/hip_runtime.h>
#include <math.h>

// ---------------------------------------------------------------------------
// GCN anomaly detector, fp32 throughout.
// Round 2 fix: the CSR build used 6.4M device-scope global atomics (k_hist +
// k_scatter) and random 4B scatter stores -> atomic serialization + 8-XCD
// dirty-line write amplification (195MB writes for a 12.8MB buffer, ~285us
// k_scatter + similar k_hist). Replaced with an atomic-free two-level
// counting sort: chunk-local LDS histograms over 196 dst-buckets -> scan ->
// reserved-range scatter of (src,dst) pairs -> per-bucket exact CSR in LDS.
// Zero global atomics; all passes streaming or block-local.
// ---------------------------------------------------------------------------

__global__ void k_detect(const unsigned int* __restrict__ w, int npairs,
                         int* __restrict__ meta) {
  __shared__ int any;
  if (threadIdx.x == 0) any = 0;
  __syncthreads();
  int local = 0;
  for (int i = threadIdx.x; i < npairs; i += blockDim.x)
    local |= (w[2 * i + 1] != 0u);
  if (local) atomicOr(&any, 1);
  __syncthreads();
  if (threadIdx.x == 0) meta[0] = any ? 0 : 1;  // 1 => edge_index is int64
}

// P1: per-chunk LDS histogram over dst buckets. hist layout: [bin][chunk].
__global__ __launch_bounds__(256) void k_binhist(const void* __restrict__ ei,
                                                 int E, int CS, int B, int shift,
                                                 const int* __restrict__ meta,
                                                 int* __restrict__ hist, int C) {
  __shared__ int lh[256];
  int c = blockIdx.x;
  for (int i = threadIdx.x; i < B; i += 256) lh[i] = 0;
  __syncthreads();
  int e0 = c * CS, e1 = min(E, e0 + CS);
  bool is64 = meta[0] != 0;
  for (int e = e0 + threadIdx.x; e < e1; e += 256) {
    int d = is64 ? (int)((const long long*)ei)[(long)E + e]
                 : ((const int*)ei)[(long)E + e];
    atomicAdd(&lh[d >> shift], 1);
  }
  __syncthreads();
  for (int b = threadIdx.x; b < B; b += 256) hist[(long)b * C + c] = lh[b];
}

// P2: single-block exclusive scan of hist[0..L), sentinel hist[L]=total.
__global__ __launch_bounds__(1024) void k_scanL(int* __restrict__ hist, int L) {
  __shared__ int sm[1024];
  int t = threadIdx.x;
  int seg = (L + 1023) >> 10;
  int i0 = t * seg, i1 = min(L, i0 + seg);
  int s = 0;
  for (int i = i0; i < i1; ++i) s += hist[i];
  sm[t] = s;
  __syncthreads();
  for (int off = 1; off < 1024; off <<= 1) {
    int x = (t >= off) ? sm[t - off] : 0;
    __syncthreads();
    sm[t] += x;
    __syncthreads();
  }
  int run = sm[t] - s;  // exclusive prefix of this thread's segment
  for (int i = i0; i < i1; ++i) { int v = hist[i]; hist[i] = run; run += v; }
  if (t == 1023) hist[L] = sm[1023];
}

// P3: re-read edges, write (src,dst) pairs into reserved per-(chunk,bin)
// ranges. LDS cursors only -> zero global atomics, ~256B contiguous runs.
__global__ __launch_bounds__(256) void k_binscatter(const void* __restrict__ ei,
                                                    int E, int CS, int B, int shift,
                                                    const int* __restrict__ meta,
                                                    const int* __restrict__ scan,
                                                    int C, int2* __restrict__ pairs) {
  __shared__ int cur[256];
  int c = blockIdx.x;
  for (int b = threadIdx.x; b < B; b += 256) cur[b] = scan[(long)b * C + c];
  __syncthreads();
  int e0 = c * CS, e1 = min(E, e0 + CS);
  bool is64 = meta[0] != 0;
  for (int e = e0 + threadIdx.x; e < e1; e += 256) {
    int s, d;
    if (is64) {
      const long long* p = (const long long*)ei;
      s = (int)p[e]; d = (int)p[(long)E + e];
    } else {
      const int* p = (const int*)ei;
      s = p[e]; d = p[(long)E + e];
    }
    int pos = atomicAdd(&cur[d >> shift], 1);
    pairs[pos] = make_int2(s, d);
  }
}

// P4a: per-bucket exact degree counts via LDS histogram (replaces k_hist).
__global__ __launch_bounds__(256) void k_bucketcnt(const int2* __restrict__ pairs,
                                                   const int* __restrict__ scan,
                                                   int C, int B, int shift, int N,
                                                   int* __restrict__ cnt) {
  __shared__ int h[1024];
  int bin = blockIdx.x;
  int base = bin << shift;
  int nn = min(N - base, 1 << shift);
  for (int i = threadIdx.x; i < nn; i += 256) h[i] = 0;
  __syncthreads();
  int p0 = scan[(long)bin * C];
  int p1 = scan[(long)(bin + 1) * C];  // sentinel gives E for last bucket
  for (int i = p0 + threadIdx.x; i < p1; i += 256)
    atomicAdd(&h[pairs[i].y - base], 1);
  __syncthreads();
  for (int i = threadIdx.x; i < nn; i += 256) cnt[base + i] = h[i];
}

// P4b: per-bucket scatter into final CSR; LDS cursors seeded from rs.
// All writes land in this block's contiguous csr region -> single-XCD lines.
__global__ __launch_bounds__(256) void k_bucketscatter(const int2* __restrict__ pairs,
                                                       const int* __restrict__ scan,
                                                       int C, int B, int shift, int N,
                                                       const int* __restrict__ rs,
                                                       int* __restrict__ csr) {
  __shared__ int cur[1024];
  int bin = blockIdx.x;
  int base = bin << shift;
  int nn = min(N - base, 1 << shift);
  for (int i = threadIdx.x; i < nn; i += 256) cur[i] = rs[base + i];
  __syncthreads();
  int p0 = scan[(long)bin * C];
  int p1 = scan[(long)(bin + 1) * C];
  for (int i = p0 + threadIdx.x; i < p1; i += 256) {
    int2 pr = pairs[i];
    int pos = atomicAdd(&cur[pr.y - base], 1);
    csr[pos] = pr.x;
  }
}

__global__ void k_dis(const int* __restrict__ cnt, float* __restrict__ dis, int n) {
  int i = blockIdx.x * blockDim.x + threadIdx.x;
  if (i < n) dis[i] = rsqrtf((float)cnt[i] + 1.0f);
}

__global__ __launch_bounds__(1024) void k_scan1(const int* __restrict__ cnt,
                                                int* __restrict__ bsums, int n) {
  __shared__ int sm[1024];
  int t = threadIdx.x;
  long i = (long)blockIdx.x * 1024 + t;
  sm[t] = (i < n) ? cnt[i] : 0;
  __syncthreads();
  for (int s = 512; s > 0; s >>= 1) {
    if (t < s) sm[t] += sm[t + s];
    __syncthreads();
  }
  if (t == 0) bsums[blockIdx.x] = sm[0];
}

__global__ void k_scan2(int* __restrict__ bsums, int nb) {
  __shared__ int sm[128];
  int t = threadIdx.x;
  int v = (t < nb) ? bsums[t] : 0;
  sm[t] = v;
  __syncthreads();
  for (int off = 1; off < 128; off <<= 1) {
    int x = (t >= off) ? sm[t - off] : 0;
    __syncthreads();
    sm[t] += x;
    __syncthreads();
  }
  if (t < nb) bsums[t] = sm[t] - v;  // exclusive
}

__global__ __launch_bounds__(1024) void k_scan3(const int* __restrict__ cnt,
                                                const int* __restrict__ bsums,
                                                int* __restrict__ rs, int n) {
  __shared__ int sm[1024];
  int t = threadIdx.x;
  long i = (long)blockIdx.x * 1024 + t;
  int v = (i < n) ? cnt[i] : 0;
  sm[t] = v;
  __syncthreads();
  for (int off = 1; off < 1024; off <<= 1) {
    int x = (t >= off) ? sm[t - off] : 0;
    __syncthreads();
    sm[t] += x;
    __syncthreads();
  }
  int excl = sm[t] - v + bsums[blockIdx.x];
  if (i < n) rs[i] = excl;
}

// C[n, M] = act(A[n, K] @ W[K, M] (+ bias)); W row-major [K][M], staged in LDS.
// K-loop pinned to no-unroll + manual next-k prefetch: 32 live A regs, no spill.
template <int K, int M, bool BIAS, int ACT>
__global__ __launch_bounds__(256) void k_gemm(const float* __restrict__ A,
                                              const float* __restrict__ W,
                                              const float* __restrict__ bias,
                                              float* __restrict__ C, int nrows) {
  constexpr int CP = 4;
  constexpr int TPR = M / CP;        // threads per row
  constexpr int RG = 256 / TPR;      // row-groups per block
  constexpr int RP = 4;              // rows per thread
  constexpr int RT = RG * RP;        // rows per block
  __shared__ __align__(16) float sW[K * M];
  __shared__ __align__(16) float sB[BIAS ? M : 4];

  for (int i = threadIdx.x; i < K * M / 4; i += 256)
    ((float4*)sW)[i] = ((const float4*)W)[i];
  if (BIAS)
    for (int i = threadIdx.x; i < M; i += 256) sB[i] = bias[i];
  __syncthreads();

  const int cg = threadIdx.x % TPR;
  const int rg = threadIdx.x / TPR;
  const long row0 = (long)blockIdx.x * RT + rg;

  const float4* Ap[RP];
  bool valid[RP];
#pragma unroll
  for (int r = 0; r < RP; ++r) {
    long row = row0 + (long)r * RG;
    valid[r] = (row < nrows);
    Ap[r] = (const float4*)(A + (valid[r] ? row : 0) * K);
  }

  float acc[RP][CP] = {};
  float4 a[RP];
#pragma unroll
  for (int r = 0; r < RP; ++r)
    a[r] = valid[r] ? Ap[r][0] : make_float4(0.f, 0.f, 0.f, 0.f);

#pragma unroll 1
  for (int k0 = 0; k0 < K - 4; k0 += 4) {
    float4 an[RP];
#pragma unroll
    for (int r = 0; r < RP; ++r)
      an[r] = valid[r] ? Ap[r][k0 / 4 + 1] : make_float4(0.f, 0.f, 0.f, 0.f);
#pragma unroll
    for (int j = 0; j < 4; ++j) {
      float4 w = ((const float4*)(sW + (k0 + j) * M))[cg];
#pragma unroll
      for (int r = 0; r < RP; ++r) {
        float av = (j == 0) ? a[r].x : (j == 1) ? a[r].y : (j == 2) ? a[r].z : a[r].w;
        acc[r][0] += av * w.x;
        acc[r][1] += av * w.y;
        acc[r][2] += av * w.z;
        acc[r][3] += av * w.w;
      }
    }
#pragma unroll
    for (int r = 0; r < RP; ++r) a[r] = an[r];
  }
  {  // last k-step
    const int k0 = K - 4;
#pragma unroll
    for (int j = 0; j < 4; ++j) {
      float4 w = ((const float4*)(sW + (k0 + j) * M))[cg];
#pragma unroll
      for (int r = 0; r < RP; ++r) {
        float av = (j == 0) ? a[r].x : (j == 1) ? a[r].y : (j == 2) ? a[r].z : a[r].w;
        acc[r][0] += av * w.x;
        acc[r][1] += av * w.y;
        acc[r][2] += av * w.z;
        acc[r][3] += av * w.w;
      }
    }
  }

#pragma unroll
  for (int r = 0; r < RP; ++r) {
    long row = row0 + (long)r * RG;
    if (row >= nrows) continue;
    float4 o = make_float4(acc[r][0], acc[r][1], acc[r][2], acc[r][3]);
    if (BIAS) {
      float4 bb = ((const float4*)sB)[cg];
      o.x += bb.x; o.y += bb.y; o.z += bb.z; o.w += bb.w;
    }
    if (ACT == 1) {
      o.x = fmaxf(o.x, 0.f); o.y = fmaxf(o.y, 0.f);
      o.z = fmaxf(o.z, 0.f); o.w = fmaxf(o.w, 0.f);
    }
    ((float4*)(C + row * M))[cg] = o;
  }
}

// Pull aggregation, D=64 features: one wave per node, lane = feature.
// 4-deep unroll: 4 independent gather rows in flight.
__global__ __launch_bounds__(256) void k_agg64(const float* __restrict__ hw,
                                               const int* __restrict__ csr,
                                               const int* __restrict__ rs,
                                               const int* __restrict__ cnt,
                                               const float* __restrict__ dis,
                                               const float* __restrict__ b,
                                               float* __restrict__ out, int n,
                                               int relu) {
  int node = blockIdx.x * 4 + (threadIdx.x >> 6);
  if (node >= n) return;
  int f = threadIdx.x & 63;
  float dsn = dis[node];
  float acc = hw[(long)node * 64 + f] * dsn * dsn;  // self-loop
  int start = rs[node], deg = cnt[node];
  int e = 0;
  for (; e + 3 < deg; e += 4) {
    int s0 = csr[start + e];
    int s1 = csr[start + e + 1];
    int s2 = csr[start + e + 2];
    int s3 = csr[start + e + 3];
    float w0 = dis[s0] * dsn, w1 = dis[s1] * dsn;
    float w2 = dis[s2] * dsn, w3 = dis[s3] * dsn;
    float v0 = hw[(long)s0 * 64 + f];
    float v1 = hw[(long)s1 * 64 + f];
    float v2 = hw[(long)s2 * 64 + f];
    float v3 = hw[(long)s3 * 64 + f];
    acc += v0 * w0 + v1 * w1 + v2 * w2 + v3 * w3;
  }
  for (; e < deg; ++e) {
    int s0 = csr[start + e];
    acc += hw[(long)s0 * 64 + f] * (dis[s0] * dsn);
  }
  float o = acc + b[f];
  out[(long)node * 64 + f] = relu ? fmaxf(o, 0.f) : o;
}

// Pull aggregation, D=32 features: two nodes per wave.
__global__ __launch_bounds__(256) void k_agg32(const float* __restrict__ hw,
                                               const int* __restrict__ csr,
                                               const int* __restrict__ rs,
                                               const int* __restrict__ cnt,
                                               const float* __restrict__ dis,
                                               const float* __restrict__ b,
                                               float* __restrict__ out, int n) {
  int node = blockIdx.x * 8 + (threadIdx.x >> 5);
  if (node >= n) return;
  int f = threadIdx.x & 31;
  float dsn = dis[node];
  float acc = hw[(long)node * 32 + f] * dsn * dsn;
  int start = rs[node], deg = cnt[node];
  int e = 0;
  for (; e + 3 < deg; e += 4) {
    int s0 = csr[start + e];
    int s1 = csr[start + e + 1];
    int s2 = csr[start + e + 2];
    int s3 = csr[start + e + 3];
    float w0 = dis[s0] * dsn, w1 = dis[s1] * dsn;
    float w2 = dis[s2] * dsn, w3 = dis[s3] * dsn;
    float v0 = hw[(long)s0 * 32 + f];
    float v1 = hw[(long)s1 * 32 + f];
    float v2 = hw[(long)s2 * 32 + f];
    float v3 = hw[(long)s3 * 32 + f];
    acc += v0 * w0 + v1 * w1 + v2 * w2 + v3 * w3;
  }
  for (; e < deg; ++e) {
    int s0 = csr[start + e];
    acc += hw[(long)s0 * 32 + f] * (dis[s0] * dsn);
  }
  out[(long)node * 32 + f] = acc + b[f];
}

// score = sigmoid(s[N,32] @ sW2[32] + sb2); 8 nodes per 256-thread block.
__global__ void k_score(const float* __restrict__ s, const float* __restrict__ sW2,
                        const float* __restrict__ sb2, float* __restrict__ out, int n) {
  int node = blockIdx.x * 8 + (threadIdx.x >> 5);
  int k = threadIdx.x & 31;
  if (node >= n) return;
  float v = s[(long)node * 32 + k] * sW2[k];
  for (int off = 16; off > 0; off >>= 1) v += __shfl_down(v, off, 32);
  if (k == 0) out[node] = 1.0f / (1.0f + expf(-(v + sb2[0])));
}

extern "C" void kernel_launch(void* const* d_in, const int* in_sizes, int n_in,
                              void* d_out, int out_size, void* d_ws, size_t ws_size,
                              hipStream_t stream) {
  const float* x   = (const float*)d_in[0];
  const void*  ei  = d_in[1];
  const float* W1  = (const float*)d_in[2];
  const float* b1  = (const float*)d_in[3];
  const float* W2  = (const float*)d_in[4];
  const float* b2  = (const float*)d_in[5];
  const float* rW1 = (const float*)d_in[6];
  const float* rb1 = (const float*)d_in[7];
  const float* rW2 = (const float*)d_in[8];
  const float* rb2 = (const float*)d_in[9];
  const float* sW1 = (const float*)d_in[10];
  const float* sb1 = (const float*)d_in[11];
  const float* sW2 = (const float*)d_in[12];
  const float* sb2 = (const float*)d_in[13];

  const int N = in_sizes[0] / 128;
  const int E = in_sizes[1] / 2;

  // bucket geometry: SPB = 1<<shift nodes per bucket, B buckets (<=256)
  int shift = 9;
  while ((((long)N + (1L << shift) - 1) >> shift) > 256) ++shift;
  const int B = (int)(((long)N + (1L << shift) - 1) >> shift);
  const int C = 512;                       // edge chunks
  const int CS = (E + C - 1) / C;          // edges per chunk
  const int L = B * C;

  // workspace layout (256B aligned chunks)
  char* w = (char*)d_ws;
  auto alloc = [&](size_t bytes) {
    char* p = w;
    w += (bytes + 255) & ~(size_t)255;
    return p;
  };
  int*   meta   = (int*)alloc(64);
  int*   cnt    = (int*)alloc((size_t)N * 4);
  int*   rs     = (int*)alloc((size_t)N * 4);
  float* dis    = (float*)alloc((size_t)N * 4);
  int*   bsums  = (int*)alloc(1024);
  int*   bscan  = (int*)alloc(((size_t)L + 1) * 4);
  int*   csr    = (int*)alloc((size_t)E * 4);
  // pairs (E*8B) aliases hw1 (N*64*4B): pairs dead before hw1 is written
  size_t uni = (size_t)E * 8 > (size_t)N * 256 ? (size_t)E * 8 : (size_t)N * 256;
  char*  u      = alloc(uni);
  int2*  pairs  = (int2*)u;
  float* hw1    = (float*)u;                          // also reused as t
  float* h1     = (float*)alloc((size_t)N * 64 * 4);
  float* hw2    = (float*)alloc((size_t)N * 32 * 4);  // also reused as s

  float* h_out = (float*)d_out;                 // [N,32]
  float* x_rec = h_out + (long)N * 32;          // [N,128]
  float* score = x_rec + (long)N * 128;         // [N,1]

  // ---- CSR build (atomic-free two-level counting sort) ----
  k_detect<<<1, 256, 0, stream>>>((const unsigned int*)ei, E < 4096 ? E : 4096, meta);
  k_binhist<<<C, 256, 0, stream>>>(ei, E, CS, B, shift, meta, bscan, C);
  k_scanL<<<1, 1024, 0, stream>>>(bscan, L);
  k_binscatter<<<C, 256, 0, stream>>>(ei, E, CS, B, shift, meta, bscan, C, pairs);
  k_bucketcnt<<<B, 256, 0, stream>>>(pairs, bscan, C, B, shift, N, cnt);
  k_dis<<<(N + 255) / 256, 256, 0, stream>>>(cnt, dis, N);
  int nb1 = (N + 1023) / 1024;
  k_scan1<<<nb1, 1024, 0, stream>>>(cnt, bsums, N);
  k_scan2<<<1, 128, 0, stream>>>(bsums, nb1);
  k_scan3<<<nb1, 1024, 0, stream>>>(cnt, bsums, rs, N);
  k_bucketscatter<<<B, 256, 0, stream>>>(pairs, bscan, C, B, shift, N, rs, csr);

  // ---- layer 1: hw1 = x @ W1 ; h1 = relu(agg + b1) ----
  k_gemm<128, 64, false, 0><<<(N + 63) / 64, 256, 0, stream>>>(x, W1, nullptr, hw1, N);
  k_agg64<<<(N + 3) / 4, 256, 0, stream>>>(hw1, csr, rs, cnt, dis, b1, h1, N, 1);

  // ---- layer 2: hw2 = h1 @ W2 ; h = agg + b2 -> d_out ----
  k_gemm<64, 32, false, 0><<<(N + 127) / 128, 256, 0, stream>>>(h1, W2, nullptr, hw2, N);
  k_agg32<<<(N + 7) / 8, 256, 0, stream>>>(hw2, csr, rs, cnt, dis, b2, h_out, N);

  // ---- reconstruction MLP: t = relu(h@rW1+rb1) ; x_rec = t@rW2+rb2 ----
  float* tbuf = hw1;
  k_gemm<32, 64, true, 1><<<(N + 63) / 64, 256, 0, stream>>>(h_out, rW1, rb1, tbuf, N);
  k_gemm<64, 128, true, 0><<<(N + 31) / 32, 256, 0, stream>>>(tbuf, rW2, rb2, x_rec, N);

  // ---- scorer MLP: s = relu(h@sW1+sb1) ; score = sigmoid(s@sW2+sb2) ----
  float* sbuf = hw2;
  k_gemm<32, 32, true, 1><<<(N + 127) / 128, 256, 0, stream>>>(h_out, sW1, sb1, sbuf, N);
  k_score<<<(N + 7) / 8, 256, 0, stream>>>(sbuf, sW2, sb2, score, N);
}

// Round 4
// 416.742 us; speedup vs baseline: 4.0308x; 1.3680x over previous
//
#include <hip/hip_runtime.h>
#include <math.h>

// ---------------------------------------------------------------------------
// GCN anomaly detector, fp32 throughout.
// Round 3 fix: k_scanL was a single-block (one CU!) serial scan of the
// 100k-entry bucket-chunk histogram -> 163us at 0.15% occupancy. Replaced
// with the same hierarchical 3-kernel scan already used for the degree
// array (k_scan1 -> k_scan2 -> k_scan3s in-place + sentinel).
// ---------------------------------------------------------------------------

__global__ void k_detect(const unsigned int* __restrict__ w, int npairs,
                         int* __restrict__ meta) {
  __shared__ int any;
  if (threadIdx.x == 0) any = 0;
  __syncthreads();
  int local = 0;
  for (int i = threadIdx.x; i < npairs; i += blockDim.x)
    local |= (w[2 * i + 1] != 0u);
  if (local) atomicOr(&any, 1);
  __syncthreads();
  if (threadIdx.x == 0) meta[0] = any ? 0 : 1;  // 1 => edge_index is int64
}

// P1: per-chunk LDS histogram over dst buckets. hist layout: [bin][chunk].
__global__ __launch_bounds__(256) void k_binhist(const void* __restrict__ ei,
                                                 int E, int CS, int B, int shift,
                                                 const int* __restrict__ meta,
                                                 int* __restrict__ hist, int C) {
  __shared__ int lh[256];
  int c = blockIdx.x;
  for (int i = threadIdx.x; i < B; i += 256) lh[i] = 0;
  __syncthreads();
  int e0 = c * CS, e1 = min(E, e0 + CS);
  bool is64 = meta[0] != 0;
  for (int e = e0 + threadIdx.x; e < e1; e += 256) {
    int d = is64 ? (int)((const long long*)ei)[(long)E + e]
                 : ((const int*)ei)[(long)E + e];
    atomicAdd(&lh[d >> shift], 1);
  }
  __syncthreads();
  for (int b = threadIdx.x; b < B; b += 256) hist[(long)b * C + c] = lh[b];
}

// P3: re-read edges, write (src,dst) pairs into reserved per-(chunk,bin)
// ranges. LDS cursors only -> zero global atomics, ~256B contiguous runs.
__global__ __launch_bounds__(256) void k_binscatter(const void* __restrict__ ei,
                                                    int E, int CS, int B, int shift,
                                                    const int* __restrict__ meta,
                                                    const int* __restrict__ scan,
                                                    int C, int2* __restrict__ pairs) {
  __shared__ int cur[256];
  int c = blockIdx.x;
  for (int b = threadIdx.x; b < B; b += 256) cur[b] = scan[(long)b * C + c];
  __syncthreads();
  int e0 = c * CS, e1 = min(E, e0 + CS);
  bool is64 = meta[0] != 0;
  for (int e = e0 + threadIdx.x; e < e1; e += 256) {
    int s, d;
    if (is64) {
      const long long* p = (const long long*)ei;
      s = (int)p[e]; d = (int)p[(long)E + e];
    } else {
      const int* p = (const int*)ei;
      s = p[e]; d = p[(long)E + e];
    }
    int pos = atomicAdd(&cur[d >> shift], 1);
    pairs[pos] = make_int2(s, d);
  }
}

// P4a: per-bucket exact degree counts via LDS histogram.
__global__ __launch_bounds__(256) void k_bucketcnt(const int2* __restrict__ pairs,
                                                   const int* __restrict__ scan,
                                                   int C, int B, int shift, int N,
                                                   int* __restrict__ cnt) {
  __shared__ int h[1024];
  int bin = blockIdx.x;
  int base = bin << shift;
  int nn = min(N - base, 1 << shift);
  for (int i = threadIdx.x; i < nn; i += 256) h[i] = 0;
  __syncthreads();
  int p0 = scan[(long)bin * C];
  int p1 = scan[(long)(bin + 1) * C];  // sentinel gives E for last bucket
  for (int i = p0 + threadIdx.x; i < p1; i += 256)
    atomicAdd(&h[pairs[i].y - base], 1);
  __syncthreads();
  for (int i = threadIdx.x; i < nn; i += 256) cnt[base + i] = h[i];
}

// P4b: per-bucket scatter into final CSR; LDS cursors seeded from rs.
// All writes land in this block's contiguous csr region -> single-XCD lines.
__global__ __launch_bounds__(256) void k_bucketscatter(const int2* __restrict__ pairs,
                                                       const int* __restrict__ scan,
                                                       int C, int B, int shift, int N,
                                                       const int* __restrict__ rs,
                                                       int* __restrict__ csr) {
  __shared__ int cur[1024];
  int bin = blockIdx.x;
  int base = bin << shift;
  int nn = min(N - base, 1 << shift);
  for (int i = threadIdx.x; i < nn; i += 256) cur[i] = rs[base + i];
  __syncthreads();
  int p0 = scan[(long)bin * C];
  int p1 = scan[(long)(bin + 1) * C];
  for (int i = p0 + threadIdx.x; i < p1; i += 256) {
    int2 pr = pairs[i];
    int pos = atomicAdd(&cur[pr.y - base], 1);
    csr[pos] = pr.x;
  }
}

__global__ void k_dis(const int* __restrict__ cnt, float* __restrict__ dis, int n) {
  int i = blockIdx.x * blockDim.x + threadIdx.x;
  if (i < n) dis[i] = rsqrtf((float)cnt[i] + 1.0f);
}

__global__ __launch_bounds__(1024) void k_scan1(const int* __restrict__ cnt,
                                                int* __restrict__ bsums, int n) {
  __shared__ int sm[1024];
  int t = threadIdx.x;
  long i = (long)blockIdx.x * 1024 + t;
  sm[t] = (i < n) ? cnt[i] : 0;
  __syncthreads();
  for (int s = 512; s > 0; s >>= 1) {
    if (t < s) sm[t] += sm[t + s];
    __syncthreads();
  }
  if (t == 0) bsums[blockIdx.x] = sm[0];
}

__global__ void k_scan2(int* __restrict__ bsums, int nb) {
  __shared__ int sm[128];
  int t = threadIdx.x;
  int v = (t < nb) ? bsums[t] : 0;
  sm[t] = v;
  __syncthreads();
  for (int off = 1; off < 128; off <<= 1) {
    int x = (t >= off) ? sm[t - off] : 0;
    __syncthreads();
    sm[t] += x;
    __syncthreads();
  }
  if (t < nb) bsums[t] = sm[t] - v;  // exclusive
}

// exclusive scan -> out (may alias in); optional sentinel out[n] = total.
__global__ __launch_bounds__(1024) void k_scan3s(const int* __restrict__ in,
                                                 const int* __restrict__ bsums,
                                                 int* __restrict__ out, int n,
                                                 int sentinel) {
  __shared__ int sm[1024];
  int t = threadIdx.x;
  long i = (long)blockIdx.x * 1024 + t;
  int v = (i < n) ? in[i] : 0;
  sm[t] = v;
  __syncthreads();
  for (int off = 1; off < 1024; off <<= 1) {
    int x = (t >= off) ? sm[t - off] : 0;
    __syncthreads();
    sm[t] += x;
    __syncthreads();
  }
  int excl = sm[t] - v + bsums[blockIdx.x];
  if (i < n) out[i] = excl;
  if (sentinel && i == n - 1) out[n] = excl + v;
}

// C[n, M] = act(A[n, K] @ W[K, M] (+ bias)); W row-major [K][M], staged in LDS.
// K-loop pinned to no-unroll + manual next-k prefetch: 32 live A regs, no spill.
template <int K, int M, bool BIAS, int ACT>
__global__ __launch_bounds__(256) void k_gemm(const float* __restrict__ A,
                                              const float* __restrict__ W,
                                              const float* __restrict__ bias,
                                              float* __restrict__ C, int nrows) {
  constexpr int CP = 4;
  constexpr int TPR = M / CP;        // threads per row
  constexpr int RG = 256 / TPR;      // row-groups per block
  constexpr int RP = 4;              // rows per thread
  constexpr int RT = RG * RP;        // rows per block
  __shared__ __align__(16) float sW[K * M];
  __shared__ __align__(16) float sB[BIAS ? M : 4];

  for (int i = threadIdx.x; i < K * M / 4; i += 256)
    ((float4*)sW)[i] = ((const float4*)W)[i];
  if (BIAS)
    for (int i = threadIdx.x; i < M; i += 256) sB[i] = bias[i];
  __syncthreads();

  const int cg = threadIdx.x % TPR;
  const int rg = threadIdx.x / TPR;
  const long row0 = (long)blockIdx.x * RT + rg;

  const float4* Ap[RP];
  bool valid[RP];
#pragma unroll
  for (int r = 0; r < RP; ++r) {
    long row = row0 + (long)r * RG;
    valid[r] = (row < nrows);
    Ap[r] = (const float4*)(A + (valid[r] ? row : 0) * K);
  }

  float acc[RP][CP] = {};
  float4 a[RP];
#pragma unroll
  for (int r = 0; r < RP; ++r)
    a[r] = valid[r] ? Ap[r][0] : make_float4(0.f, 0.f, 0.f, 0.f);

#pragma unroll 1
  for (int k0 = 0; k0 < K - 4; k0 += 4) {
    float4 an[RP];
#pragma unroll
    for (int r = 0; r < RP; ++r)
      an[r] = valid[r] ? Ap[r][k0 / 4 + 1] : make_float4(0.f, 0.f, 0.f, 0.f);
#pragma unroll
    for (int j = 0; j < 4; ++j) {
      float4 w = ((const float4*)(sW + (k0 + j) * M))[cg];
#pragma unroll
      for (int r = 0; r < RP; ++r) {
        float av = (j == 0) ? a[r].x : (j == 1) ? a[r].y : (j == 2) ? a[r].z : a[r].w;
        acc[r][0] += av * w.x;
        acc[r][1] += av * w.y;
        acc[r][2] += av * w.z;
        acc[r][3] += av * w.w;
      }
    }
#pragma unroll
    for (int r = 0; r < RP; ++r) a[r] = an[r];
  }
  {  // last k-step
    const int k0 = K - 4;
#pragma unroll
    for (int j = 0; j < 4; ++j) {
      float4 w = ((const float4*)(sW + (k0 + j) * M))[cg];
#pragma unroll
      for (int r = 0; r < RP; ++r) {
        float av = (j == 0) ? a[r].x : (j == 1) ? a[r].y : (j == 2) ? a[r].z : a[r].w;
        acc[r][0] += av * w.x;
        acc[r][1] += av * w.y;
        acc[r][2] += av * w.z;
        acc[r][3] += av * w.w;
      }
    }
  }

#pragma unroll
  for (int r = 0; r < RP; ++r) {
    long row = row0 + (long)r * RG;
    if (row >= nrows) continue;
    float4 o = make_float4(acc[r][0], acc[r][1], acc[r][2], acc[r][3]);
    if (BIAS) {
      float4 bb = ((const float4*)sB)[cg];
      o.x += bb.x; o.y += bb.y; o.z += bb.z; o.w += bb.w;
    }
    if (ACT == 1) {
      o.x = fmaxf(o.x, 0.f); o.y = fmaxf(o.y, 0.f);
      o.z = fmaxf(o.z, 0.f); o.w = fmaxf(o.w, 0.f);
    }
    ((float4*)(C + row * M))[cg] = o;
  }
}

// Pull aggregation, D=64 features: one wave per node, lane = feature.
// 4-deep unroll: 4 independent gather rows in flight.
__global__ __launch_bounds__(256) void k_agg64(const float* __restrict__ hw,
                                               const int* __restrict__ csr,
                                               const int* __restrict__ rs,
                                               const int* __restrict__ cnt,
                                               const float* __restrict__ dis,
                                               const float* __restrict__ b,
                                               float* __restrict__ out, int n,
                                               int relu) {
  int node = blockIdx.x * 4 + (threadIdx.x >> 6);
  if (node >= n) return;
  int f = threadIdx.x & 63;
  float dsn = dis[node];
  float acc = hw[(long)node * 64 + f] * dsn * dsn;  // self-loop
  int start = rs[node], deg = cnt[node];
  int e = 0;
  for (; e + 3 < deg; e += 4) {
    int s0 = csr[start + e];
    int s1 = csr[start + e + 1];
    int s2 = csr[start + e + 2];
    int s3 = csr[start + e + 3];
    float w0 = dis[s0] * dsn, w1 = dis[s1] * dsn;
    float w2 = dis[s2] * dsn, w3 = dis[s3] * dsn;
    float v0 = hw[(long)s0 * 64 + f];
    float v1 = hw[(long)s1 * 64 + f];
    float v2 = hw[(long)s2 * 64 + f];
    float v3 = hw[(long)s3 * 64 + f];
    acc += v0 * w0 + v1 * w1 + v2 * w2 + v3 * w3;
  }
  for (; e < deg; ++e) {
    int s0 = csr[start + e];
    acc += hw[(long)s0 * 64 + f] * (dis[s0] * dsn);
  }
  float o = acc + b[f];
  out[(long)node * 64 + f] = relu ? fmaxf(o, 0.f) : o;
}

// Pull aggregation, D=32 features: two nodes per wave.
__global__ __launch_bounds__(256) void k_agg32(const float* __restrict__ hw,
                                               const int* __restrict__ csr,
                                               const int* __restrict__ rs,
                                               const int* __restrict__ cnt,
                                               const float* __restrict__ dis,
                                               const float* __restrict__ b,
                                               float* __restrict__ out, int n) {
  int node = blockIdx.x * 8 + (threadIdx.x >> 5);
  if (node >= n) return;
  int f = threadIdx.x & 31;
  float dsn = dis[node];
  float acc = hw[(long)node * 32 + f] * dsn * dsn;
  int start = rs[node], deg = cnt[node];
  int e = 0;
  for (; e + 3 < deg; e += 4) {
    int s0 = csr[start + e];
    int s1 = csr[start + e + 1];
    int s2 = csr[start + e + 2];
    int s3 = csr[start + e + 3];
    float w0 = dis[s0] * dsn, w1 = dis[s1] * dsn;
    float w2 = dis[s2] * dsn, w3 = dis[s3] * dsn;
    float v0 = hw[(long)s0 * 32 + f];
    float v1 = hw[(long)s1 * 32 + f];
    float v2 = hw[(long)s2 * 32 + f];
    float v3 = hw[(long)s3 * 32 + f];
    acc += v0 * w0 + v1 * w1 + v2 * w2 + v3 * w3;
  }
  for (; e < deg; ++e) {
    int s0 = csr[start + e];
    acc += hw[(long)s0 * 32 + f] * (dis[s0] * dsn);
  }
  out[(long)node * 32 + f] = acc + b[f];
}

// score = sigmoid(s[N,32] @ sW2[32] + sb2); 8 nodes per 256-thread block.
__global__ void k_score(const float* __restrict__ s, const float* __restrict__ sW2,
                        const float* __restrict__ sb2, float* __restrict__ out, int n) {
  int node = blockIdx.x * 8 + (threadIdx.x >> 5);
  int k = threadIdx.x & 31;
  if (node >= n) return;
  float v = s[(long)node * 32 + k] * sW2[k];
  for (int off = 16; off > 0; off >>= 1) v += __shfl_down(v, off, 32);
  if (k == 0) out[node] = 1.0f / (1.0f + expf(-(v + sb2[0])));
}

extern "C" void kernel_launch(void* const* d_in, const int* in_sizes, int n_in,
                              void* d_out, int out_size, void* d_ws, size_t ws_size,
                              hipStream_t stream) {
  const float* x   = (const float*)d_in[0];
  const void*  ei  = d_in[1];
  const float* W1  = (const float*)d_in[2];
  const float* b1  = (const float*)d_in[3];
  const float* W2  = (const float*)d_in[4];
  const float* b2  = (const float*)d_in[5];
  const float* rW1 = (const float*)d_in[6];
  const float* rb1 = (const float*)d_in[7];
  const float* rW2 = (const float*)d_in[8];
  const float* rb2 = (const float*)d_in[9];
  const float* sW1 = (const float*)d_in[10];
  const float* sb1 = (const float*)d_in[11];
  const float* sW2 = (const float*)d_in[12];
  const float* sb2 = (const float*)d_in[13];

  const int N = in_sizes[0] / 128;
  const int E = in_sizes[1] / 2;

  // bucket geometry: SPB = 1<<shift nodes per bucket, B buckets (<=256)
  int shift = 9;
  while ((((long)N + (1L << shift) - 1) >> shift) > 256) ++shift;
  const int B = (int)(((long)N + (1L << shift) - 1) >> shift);
  const int C = 512;                       // edge chunks
  const int CS = (E + C - 1) / C;          // edges per chunk
  const int L = B * C;

  // workspace layout (256B aligned chunks)
  char* w = (char*)d_ws;
  auto alloc = [&](size_t bytes) {
    char* p = w;
    w += (bytes + 255) & ~(size_t)255;
    return p;
  };
  int*   meta   = (int*)alloc(64);
  int*   cnt    = (int*)alloc((size_t)N * 4);
  int*   rs     = (int*)alloc((size_t)N * 4);
  float* dis    = (float*)alloc((size_t)N * 4);
  int*   bsums  = (int*)alloc(1024);
  int*   bsumsL = (int*)alloc(1024);
  int*   bscan  = (int*)alloc(((size_t)L + 1) * 4);
  int*   csr    = (int*)alloc((size_t)E * 4);
  // pairs (E*8B) aliases hw1 (N*64*4B): pairs dead before hw1 is written
  size_t uni = (size_t)E * 8 > (size_t)N * 256 ? (size_t)E * 8 : (size_t)N * 256;
  char*  u      = alloc(uni);
  int2*  pairs  = (int2*)u;
  float* hw1    = (float*)u;                          // also reused as t
  float* h1     = (float*)alloc((size_t)N * 64 * 4);
  float* hw2    = (float*)alloc((size_t)N * 32 * 4);  // also reused as s

  float* h_out = (float*)d_out;                 // [N,32]
  float* x_rec = h_out + (long)N * 32;          // [N,128]
  float* score = x_rec + (long)N * 128;         // [N,1]

  // ---- CSR build (atomic-free two-level counting sort) ----
  k_detect<<<1, 256, 0, stream>>>((const unsigned int*)ei, E < 4096 ? E : 4096, meta);
  k_binhist<<<C, 256, 0, stream>>>(ei, E, CS, B, shift, meta, bscan, C);
  int nbL = (L + 1023) / 1024;
  k_scan1<<<nbL, 1024, 0, stream>>>(bscan, bsumsL, L);
  k_scan2<<<1, 128, 0, stream>>>(bsumsL, nbL);
  k_scan3s<<<nbL, 1024, 0, stream>>>(bscan, bsumsL, bscan, L, 1);  // in-place + sentinel
  k_binscatter<<<C, 256, 0, stream>>>(ei, E, CS, B, shift, meta, bscan, C, pairs);
  k_bucketcnt<<<B, 256, 0, stream>>>(pairs, bscan, C, B, shift, N, cnt);
  k_dis<<<(N + 255) / 256, 256, 0, stream>>>(cnt, dis, N);
  int nb1 = (N + 1023) / 1024;
  k_scan1<<<nb1, 1024, 0, stream>>>(cnt, bsums, N);
  k_scan2<<<1, 128, 0, stream>>>(bsums, nb1);
  k_scan3s<<<nb1, 1024, 0, stream>>>(cnt, bsums, rs, N, 0);
  k_bucketscatter<<<B, 256, 0, stream>>>(pairs, bscan, C, B, shift, N, rs, csr);

  // ---- layer 1: hw1 = x @ W1 ; h1 = relu(agg + b1) ----
  k_gemm<128, 64, false, 0><<<(N + 63) / 64, 256, 0, stream>>>(x, W1, nullptr, hw1, N);
  k_agg64<<<(N + 3) / 4, 256, 0, stream>>>(hw1, csr, rs, cnt, dis, b1, h1, N, 1);

  // ---- layer 2: hw2 = h1 @ W2 ; h = agg + b2 -> d_out ----
  k_gemm<64, 32, false, 0><<<(N + 127) / 128, 256, 0, stream>>>(h1, W2, nullptr, hw2, N);
  k_agg32<<<(N + 7) / 8, 256, 0, stream>>>(hw2, csr, rs, cnt, dis, b2, h_out, N);

  // ---- reconstruction MLP: t = relu(h@rW1+rb1) ; x_rec = t@rW2+rb2 ----
  float* tbuf = hw1;
  k_gemm<32, 64, true, 1><<<(N + 63) / 64, 256, 0, stream>>>(h_out, rW1, rb1, tbuf, N);
  k_gemm<64, 128, true, 0><<<(N + 31) / 32, 256, 0, stream>>>(tbuf, rW2, rb2, x_rec, N);

  // ---- scorer MLP: s = relu(h@sW1+sb1) ; score = sigmoid(s@sW2+sb2) ----
  float* sbuf = hw2;
  k_gemm<32, 32, true, 1><<<(N + 127) / 128, 256, 0, stream>>>(h_out, sW1, sb1, sbuf, N);
  k_score<<<(N + 7) / 8, 256, 0, stream>>>(sbuf, sW2, sb2, score, N);
}

// Round 5
// 397.384 us; speedup vs baseline: 4.2272x; 1.0487x over previous
//
#include <hip/hip_runtime.h>
#include <hip/hip_bf16.h>
#include <math.h>

// ---------------------------------------------------------------------------
// GCN anomaly detector.
// Round 4 fix: k_agg64 gathered 819MB of fp32 feature rows (372MB L2-miss
// per dispatch, 124us @ 41% HBM peak). The pre-aggregation features hw1/hw2
// are now stored bf16 (written directly by the GEMM epilogue): halves the
// gathered bytes AND the gather footprint (25.6->12.8MB, better L2 fit).
// All accumulation stays fp32; bf16 RNE adds ~1e-3 worst-case error vs
// 9.2e-3 threshold.
// ---------------------------------------------------------------------------

__global__ void k_detect(const unsigned int* __restrict__ w, int npairs,
                         int* __restrict__ meta) {
  __shared__ int any;
  if (threadIdx.x == 0) any = 0;
  __syncthreads();
  int local = 0;
  for (int i = threadIdx.x; i < npairs; i += blockDim.x)
    local |= (w[2 * i + 1] != 0u);
  if (local) atomicOr(&any, 1);
  __syncthreads();
  if (threadIdx.x == 0) meta[0] = any ? 0 : 1;  // 1 => edge_index is int64
}

// P1: per-chunk LDS histogram over dst buckets. hist layout: [bin][chunk].
__global__ __launch_bounds__(256) void k_binhist(const void* __restrict__ ei,
                                                 int E, int CS, int B, int shift,
                                                 const int* __restrict__ meta,
                                                 int* __restrict__ hist, int C) {
  __shared__ int lh[256];
  int c = blockIdx.x;
  for (int i = threadIdx.x; i < B; i += 256) lh[i] = 0;
  __syncthreads();
  int e0 = c * CS, e1 = min(E, e0 + CS);
  bool is64 = meta[0] != 0;
  for (int e = e0 + threadIdx.x; e < e1; e += 256) {
    int d = is64 ? (int)((const long long*)ei)[(long)E + e]
                 : ((const int*)ei)[(long)E + e];
    atomicAdd(&lh[d >> shift], 1);
  }
  __syncthreads();
  for (int b = threadIdx.x; b < B; b += 256) hist[(long)b * C + c] = lh[b];
}

// P3: re-read edges, write (src,dst) pairs into reserved per-(chunk,bin)
// ranges. LDS cursors only -> zero global atomics, ~256B contiguous runs.
__global__ __launch_bounds__(256) void k_binscatter(const void* __restrict__ ei,
                                                    int E, int CS, int B, int shift,
                                                    const int* __restrict__ meta,
                                                    const int* __restrict__ scan,
                                                    int C, int2* __restrict__ pairs) {
  __shared__ int cur[256];
  int c = blockIdx.x;
  for (int b = threadIdx.x; b < B; b += 256) cur[b] = scan[(long)b * C + c];
  __syncthreads();
  int e0 = c * CS, e1 = min(E, e0 + CS);
  bool is64 = meta[0] != 0;
  for (int e = e0 + threadIdx.x; e < e1; e += 256) {
    int s, d;
    if (is64) {
      const long long* p = (const long long*)ei;
      s = (int)p[e]; d = (int)p[(long)E + e];
    } else {
      const int* p = (const int*)ei;
      s = p[e]; d = p[(long)E + e];
    }
    int pos = atomicAdd(&cur[d >> shift], 1);
    pairs[pos] = make_int2(s, d);
  }
}

// P4a: per-bucket exact degree counts via LDS histogram.
__global__ __launch_bounds__(256) void k_bucketcnt(const int2* __restrict__ pairs,
                                                   const int* __restrict__ scan,
                                                   int C, int B, int shift, int N,
                                                   int* __restrict__ cnt) {
  __shared__ int h[1024];
  int bin = blockIdx.x;
  int base = bin << shift;
  int nn = min(N - base, 1 << shift);
  for (int i = threadIdx.x; i < nn; i += 256) h[i] = 0;
  __syncthreads();
  int p0 = scan[(long)bin * C];
  int p1 = scan[(long)(bin + 1) * C];  // sentinel gives E for last bucket
  for (int i = p0 + threadIdx.x; i < p1; i += 256)
    atomicAdd(&h[pairs[i].y - base], 1);
  __syncthreads();
  for (int i = threadIdx.x; i < nn; i += 256) cnt[base + i] = h[i];
}

// P4b: per-bucket scatter into final CSR; LDS cursors seeded from rs.
__global__ __launch_bounds__(256) void k_bucketscatter(const int2* __restrict__ pairs,
                                                       const int* __restrict__ scan,
                                                       int C, int B, int shift, int N,
                                                       const int* __restrict__ rs,
                                                       int* __restrict__ csr) {
  __shared__ int cur[1024];
  int bin = blockIdx.x;
  int base = bin << shift;
  int nn = min(N - base, 1 << shift);
  for (int i = threadIdx.x; i < nn; i += 256) cur[i] = rs[base + i];
  __syncthreads();
  int p0 = scan[(long)bin * C];
  int p1 = scan[(long)(bin + 1) * C];
  for (int i = p0 + threadIdx.x; i < p1; i += 256) {
    int2 pr = pairs[i];
    int pos = atomicAdd(&cur[pr.y - base], 1);
    csr[pos] = pr.x;
  }
}

__global__ void k_dis(const int* __restrict__ cnt, float* __restrict__ dis, int n) {
  int i = blockIdx.x * blockDim.x + threadIdx.x;
  if (i < n) dis[i] = rsqrtf((float)cnt[i] + 1.0f);
}

__global__ __launch_bounds__(1024) void k_scan1(const int* __restrict__ cnt,
                                                int* __restrict__ bsums, int n) {
  __shared__ int sm[1024];
  int t = threadIdx.x;
  long i = (long)blockIdx.x * 1024 + t;
  sm[t] = (i < n) ? cnt[i] : 0;
  __syncthreads();
  for (int s = 512; s > 0; s >>= 1) {
    if (t < s) sm[t] += sm[t + s];
    __syncthreads();
  }
  if (t == 0) bsums[blockIdx.x] = sm[0];
}

__global__ void k_scan2(int* __restrict__ bsums, int nb) {
  __shared__ int sm[128];
  int t = threadIdx.x;
  int v = (t < nb) ? bsums[t] : 0;
  sm[t] = v;
  __syncthreads();
  for (int off = 1; off < 128; off <<= 1) {
    int x = (t >= off) ? sm[t - off] : 0;
    __syncthreads();
    sm[t] += x;
    __syncthreads();
  }
  if (t < nb) bsums[t] = sm[t] - v;  // exclusive
}

// exclusive scan -> out (may alias in); optional sentinel out[n] = total.
__global__ __launch_bounds__(1024) void k_scan3s(const int* __restrict__ in,
                                                 const int* __restrict__ bsums,
                                                 int* __restrict__ out, int n,
                                                 int sentinel) {
  __shared__ int sm[1024];
  int t = threadIdx.x;
  long i = (long)blockIdx.x * 1024 + t;
  int v = (i < n) ? in[i] : 0;
  sm[t] = v;
  __syncthreads();
  for (int off = 1; off < 1024; off <<= 1) {
    int x = (t >= off) ? sm[t - off] : 0;
    __syncthreads();
    sm[t] += x;
    __syncthreads();
  }
  int excl = sm[t] - v + bsums[blockIdx.x];
  if (i < n) out[i] = excl;
  if (sentinel && i == n - 1) out[n] = excl + v;
}

// C[n, M] = act(A[n, K] @ W[K, M] (+ bias)); W row-major [K][M], staged in LDS.
// K-loop pinned to no-unroll + manual next-k prefetch: 32 live A regs, no spill.
// OBF16: write output as bf16 (RNE) instead of fp32.
template <int K, int M, bool BIAS, int ACT, bool OBF16>
__global__ __launch_bounds__(256) void k_gemm(const float* __restrict__ A,
                                              const float* __restrict__ W,
                                              const float* __restrict__ bias,
                                              void* __restrict__ Cout, int nrows) {
  constexpr int CP = 4;
  constexpr int TPR = M / CP;        // threads per row
  constexpr int RG = 256 / TPR;      // row-groups per block
  constexpr int RP = 4;              // rows per thread
  constexpr int RT = RG * RP;        // rows per block
  __shared__ __align__(16) float sW[K * M];
  __shared__ __align__(16) float sB[BIAS ? M : 4];

  for (int i = threadIdx.x; i < K * M / 4; i += 256)
    ((float4*)sW)[i] = ((const float4*)W)[i];
  if (BIAS)
    for (int i = threadIdx.x; i < M; i += 256) sB[i] = bias[i];
  __syncthreads();

  const int cg = threadIdx.x % TPR;
  const int rg = threadIdx.x / TPR;
  const long row0 = (long)blockIdx.x * RT + rg;

  const float4* Ap[RP];
  bool valid[RP];
#pragma unroll
  for (int r = 0; r < RP; ++r) {
    long row = row0 + (long)r * RG;
    valid[r] = (row < nrows);
    Ap[r] = (const float4*)(A + (valid[r] ? row : 0) * K);
  }

  float acc[RP][CP] = {};
  float4 a[RP];
#pragma unroll
  for (int r = 0; r < RP; ++r)
    a[r] = valid[r] ? Ap[r][0] : make_float4(0.f, 0.f, 0.f, 0.f);

#pragma unroll 1
  for (int k0 = 0; k0 < K - 4; k0 += 4) {
    float4 an[RP];
#pragma unroll
    for (int r = 0; r < RP; ++r)
      an[r] = valid[r] ? Ap[r][k0 / 4 + 1] : make_float4(0.f, 0.f, 0.f, 0.f);
#pragma unroll
    for (int j = 0; j < 4; ++j) {
      float4 w = ((const float4*)(sW + (k0 + j) * M))[cg];
#pragma unroll
      for (int r = 0; r < RP; ++r) {
        float av = (j == 0) ? a[r].x : (j == 1) ? a[r].y : (j == 2) ? a[r].z : a[r].w;
        acc[r][0] += av * w.x;
        acc[r][1] += av * w.y;
        acc[r][2] += av * w.z;
        acc[r][3] += av * w.w;
      }
    }
#pragma unroll
    for (int r = 0; r < RP; ++r) a[r] = an[r];
  }
  {  // last k-step
    const int k0 = K - 4;
#pragma unroll
    for (int j = 0; j < 4; ++j) {
      float4 w = ((const float4*)(sW + (k0 + j) * M))[cg];
#pragma unroll
      for (int r = 0; r < RP; ++r) {
        float av = (j == 0) ? a[r].x : (j == 1) ? a[r].y : (j == 2) ? a[r].z : a[r].w;
        acc[r][0] += av * w.x;
        acc[r][1] += av * w.y;
        acc[r][2] += av * w.z;
        acc[r][3] += av * w.w;
      }
    }
  }

#pragma unroll
  for (int r = 0; r < RP; ++r) {
    long row = row0 + (long)r * RG;
    if (row >= nrows) continue;
    float4 o = make_float4(acc[r][0], acc[r][1], acc[r][2], acc[r][3]);
    if (BIAS) {
      float4 bb = ((const float4*)sB)[cg];
      o.x += bb.x; o.y += bb.y; o.z += bb.z; o.w += bb.w;
    }
    if (ACT == 1) {
      o.x = fmaxf(o.x, 0.f); o.y = fmaxf(o.y, 0.f);
      o.z = fmaxf(o.z, 0.f); o.w = fmaxf(o.w, 0.f);
    }
    if (OBF16) {
      __hip_bfloat16 b0 = __float2bfloat16(o.x);
      __hip_bfloat16 b1 = __float2bfloat16(o.y);
      __hip_bfloat16 b2 = __float2bfloat16(o.z);
      __hip_bfloat16 b3 = __float2bfloat16(o.w);
      ushort4 pk;
      pk.x = *(unsigned short*)&b0;
      pk.y = *(unsigned short*)&b1;
      pk.z = *(unsigned short*)&b2;
      pk.w = *(unsigned short*)&b3;
      ((ushort4*)((__hip_bfloat16*)Cout + row * M))[cg] = pk;
    } else {
      ((float4*)((float*)Cout + row * M))[cg] = o;
    }
  }
}

// Pull aggregation, D=64 bf16 features: one wave per node, lane = feature.
__global__ __launch_bounds__(256) void k_agg64b(const __hip_bfloat16* __restrict__ hw,
                                                const int* __restrict__ csr,
                                                const int* __restrict__ rs,
                                                const int* __restrict__ cnt,
                                                const float* __restrict__ dis,
                                                const float* __restrict__ b,
                                                float* __restrict__ out, int n,
                                                int relu) {
  int node = blockIdx.x * 4 + (threadIdx.x >> 6);
  if (node >= n) return;
  int f = threadIdx.x & 63;
  float dsn = dis[node];
  float acc = __bfloat162float(hw[(long)node * 64 + f]) * dsn * dsn;  // self-loop
  int start = rs[node], deg = cnt[node];
  int e = 0;
  for (; e + 3 < deg; e += 4) {
    int s0 = csr[start + e];
    int s1 = csr[start + e + 1];
    int s2 = csr[start + e + 2];
    int s3 = csr[start + e + 3];
    float w0 = dis[s0] * dsn, w1 = dis[s1] * dsn;
    float w2 = dis[s2] * dsn, w3 = dis[s3] * dsn;
    float v0 = __bfloat162float(hw[(long)s0 * 64 + f]);
    float v1 = __bfloat162float(hw[(long)s1 * 64 + f]);
    float v2 = __bfloat162float(hw[(long)s2 * 64 + f]);
    float v3 = __bfloat162float(hw[(long)s3 * 64 + f]);
    acc += v0 * w0 + v1 * w1 + v2 * w2 + v3 * w3;
  }
  for (; e < deg; ++e) {
    int s0 = csr[start + e];
    acc += __bfloat162float(hw[(long)s0 * 64 + f]) * (dis[s0] * dsn);
  }
  float o = acc + b[f];
  out[(long)node * 64 + f] = relu ? fmaxf(o, 0.f) : o;
}

// Pull aggregation, D=32 bf16 features: two nodes per wave.
__global__ __launch_bounds__(256) void k_agg32b(const __hip_bfloat16* __restrict__ hw,
                                                const int* __restrict__ csr,
                                                const int* __restrict__ rs,
                                                const int* __restrict__ cnt,
                                                const float* __restrict__ dis,
                                                const float* __restrict__ b,
                                                float* __restrict__ out, int n) {
  int node = blockIdx.x * 8 + (threadIdx.x >> 5);
  if (node >= n) return;
  int f = threadIdx.x & 31;
  float dsn = dis[node];
  float acc = __bfloat162float(hw[(long)node * 32 + f]) * dsn * dsn;
  int start = rs[node], deg = cnt[node];
  int e = 0;
  for (; e + 3 < deg; e += 4) {
    int s0 = csr[start + e];
    int s1 = csr[start + e + 1];
    int s2 = csr[start + e + 2];
    int s3 = csr[start + e + 3];
    float w0 = dis[s0] * dsn, w1 = dis[s1] * dsn;
    float w2 = dis[s2] * dsn, w3 = dis[s3] * dsn;
    float v0 = __bfloat162float(hw[(long)s0 * 32 + f]);
    float v1 = __bfloat162float(hw[(long)s1 * 32 + f]);
    float v2 = __bfloat162float(hw[(long)s2 * 32 + f]);
    float v3 = __bfloat162float(hw[(long)s3 * 32 + f]);
    acc += v0 * w0 + v1 * w1 + v2 * w2 + v3 * w3;
  }
  for (; e < deg; ++e) {
    int s0 = csr[start + e];
    acc += __bfloat162float(hw[(long)s0 * 32 + f]) * (dis[s0] * dsn);
  }
  out[(long)node * 32 + f] = acc + b[f];
}

// score = sigmoid(s[N,32] @ sW2[32] + sb2); 8 nodes per 256-thread block.
__global__ void k_score(const float* __restrict__ s, const float* __restrict__ sW2,
                        const float* __restrict__ sb2, float* __restrict__ out, int n) {
  int node = blockIdx.x * 8 + (threadIdx.x >> 5);
  int k = threadIdx.x & 31;
  if (node >= n) return;
  float v = s[(long)node * 32 + k] * sW2[k];
  for (int off = 16; off > 0; off >>= 1) v += __shfl_down(v, off, 32);
  if (k == 0) out[node] = 1.0f / (1.0f + expf(-(v + sb2[0])));
}

extern "C" void kernel_launch(void* const* d_in, const int* in_sizes, int n_in,
                              void* d_out, int out_size, void* d_ws, size_t ws_size,
                              hipStream_t stream) {
  const float* x   = (const float*)d_in[0];
  const void*  ei  = d_in[1];
  const float* W1  = (const float*)d_in[2];
  const float* b1  = (const float*)d_in[3];
  const float* W2  = (const float*)d_in[4];
  const float* b2  = (const float*)d_in[5];
  const float* rW1 = (const float*)d_in[6];
  const float* rb1 = (const float*)d_in[7];
  const float* rW2 = (const float*)d_in[8];
  const float* rb2 = (const float*)d_in[9];
  const float* sW1 = (const float*)d_in[10];
  const float* sb1 = (const float*)d_in[11];
  const float* sW2 = (const float*)d_in[12];
  const float* sb2 = (const float*)d_in[13];

  const int N = in_sizes[0] / 128;
  const int E = in_sizes[1] / 2;

  // bucket geometry: SPB = 1<<shift nodes per bucket, B buckets (<=256)
  int shift = 9;
  while ((((long)N + (1L << shift) - 1) >> shift) > 256) ++shift;
  const int B = (int)(((long)N + (1L << shift) - 1) >> shift);
  const int C = 512;                       // edge chunks
  const int CS = (E + C - 1) / C;          // edges per chunk
  const int L = B * C;

  // workspace layout (256B aligned chunks)
  char* w = (char*)d_ws;
  auto alloc = [&](size_t bytes) {
    char* p = w;
    w += (bytes + 255) & ~(size_t)255;
    return p;
  };
  int*   meta   = (int*)alloc(64);
  int*   cnt    = (int*)alloc((size_t)N * 4);
  int*   rs     = (int*)alloc((size_t)N * 4);
  float* dis    = (float*)alloc((size_t)N * 4);
  int*   bsums  = (int*)alloc(1024);
  int*   bsumsL = (int*)alloc(1024);
  int*   bscan  = (int*)alloc(((size_t)L + 1) * 4);
  int*   csr    = (int*)alloc((size_t)E * 4);
  // union buffer: pairs (E*8B) -> later tbuf (N*64*4B fp32) -> later sbuf
  size_t uni = (size_t)E * 8 > (size_t)N * 256 ? (size_t)E * 8 : (size_t)N * 256;
  char*  u      = alloc(uni);
  int2*  pairs  = (int2*)u;
  float* tbuf   = (float*)u;                 // recon intermediate [N,64] fp32
  float* sbuf   = (float*)u;                 // scorer intermediate [N,32] fp32
  __hip_bfloat16* hw1 = (__hip_bfloat16*)alloc((size_t)N * 64 * 2);  // bf16
  float* h1     = (float*)alloc((size_t)N * 64 * 4);
  __hip_bfloat16* hw2 = (__hip_bfloat16*)alloc((size_t)N * 32 * 2);  // bf16

  float* h_out = (float*)d_out;                 // [N,32]
  float* x_rec = h_out + (long)N * 32;          // [N,128]
  float* score = x_rec + (long)N * 128;         // [N,1]

  // ---- CSR build (atomic-free two-level counting sort) ----
  k_detect<<<1, 256, 0, stream>>>((const unsigned int*)ei, E < 4096 ? E : 4096, meta);
  k_binhist<<<C, 256, 0, stream>>>(ei, E, CS, B, shift, meta, bscan, C);
  int nbL = (L + 1023) / 1024;
  k_scan1<<<nbL, 1024, 0, stream>>>(bscan, bsumsL, L);
  k_scan2<<<1, 128, 0, stream>>>(bsumsL, nbL);
  k_scan3s<<<nbL, 1024, 0, stream>>>(bscan, bsumsL, bscan, L, 1);  // in-place + sentinel
  k_binscatter<<<C, 256, 0, stream>>>(ei, E, CS, B, shift, meta, bscan, C, pairs);
  k_bucketcnt<<<B, 256, 0, stream>>>(pairs, bscan, C, B, shift, N, cnt);
  k_dis<<<(N + 255) / 256, 256, 0, stream>>>(cnt, dis, N);
  int nb1 = (N + 1023) / 1024;
  k_scan1<<<nb1, 1024, 0, stream>>>(cnt, bsums, N);
  k_scan2<<<1, 128, 0, stream>>>(bsums, nb1);
  k_scan3s<<<nb1, 1024, 0, stream>>>(cnt, bsums, rs, N, 0);
  k_bucketscatter<<<B, 256, 0, stream>>>(pairs, bscan, C, B, shift, N, rs, csr);

  // ---- layer 1: hw1 = bf16(x @ W1) ; h1 = relu(agg + b1) ----
  k_gemm<128, 64, false, 0, true><<<(N + 63) / 64, 256, 0, stream>>>(x, W1, nullptr, hw1, N);
  k_agg64b<<<(N + 3) / 4, 256, 0, stream>>>(hw1, csr, rs, cnt, dis, b1, h1, N, 1);

  // ---- layer 2: hw2 = bf16(h1 @ W2) ; h = agg + b2 -> d_out ----
  k_gemm<64, 32, false, 0, true><<<(N + 127) / 128, 256, 0, stream>>>(h1, W2, nullptr, hw2, N);
  k_agg32b<<<(N + 7) / 8, 256, 0, stream>>>(hw2, csr, rs, cnt, dis, b2, h_out, N);

  // ---- reconstruction MLP: t = relu(h@rW1+rb1) ; x_rec = t@rW2+rb2 ----
  k_gemm<32, 64, true, 1, false><<<(N + 63) / 64, 256, 0, stream>>>(h_out, rW1, rb1, tbuf, N);
  k_gemm<64, 128, true, 0, false><<<(N + 31) / 32, 256, 0, stream>>>(tbuf, rW2, rb2, x_rec, N);

  // ---- scorer MLP: s = relu(h@sW1+sb1) ; score = sigmoid(s@sW2+sb2) ----
  // sbuf aliases tbuf's buffer (tbuf dead after x_rec GEMM)
  k_gemm<32, 32, true, 1, false><<<(N + 127) / 128, 256, 0, stream>>>(h_out, sW1, sb1, sbuf, N);
  k_score<<<(N + 7) / 8, 256, 0, stream>>>(sbuf, sW2, sb2, score, N);
}

// Round 6
// 337.488 us; speedup vs baseline: 4.9774x; 1.1775x over previous
//
#include <hip/hip_runtime.h>
#include <hip/hip_bf16.h>
#include <math.h>

// ---------------------------------------------------------------------------
// GCN anomaly detector.
// Round 5 fix: agg kernels were gather-ISSUE bound (111us @ only 22% HBM,
// VALUBusy 46%): 2B/lane gathers + 64-bit addr arithmetic. Now: packed
// bf16x2 per lane (one u32 load gathers 2 features; 2 nodes per wave for
// D=64, 4 for D=32), bit-op bf16->f32 unpack, 32-bit index math. Also fused
// cnt/dis/rs production into one per-bucket kernel (kills 4 dispatches).
// ---------------------------------------------------------------------------

__global__ void k_detect(const unsigned int* __restrict__ w, int npairs,
                         int* __restrict__ meta) {
  __shared__ int any;
  if (threadIdx.x == 0) any = 0;
  __syncthreads();
  int local = 0;
  for (int i = threadIdx.x; i < npairs; i += blockDim.x)
    local |= (w[2 * i + 1] != 0u);
  if (local) atomicOr(&any, 1);
  __syncthreads();
  if (threadIdx.x == 0) meta[0] = any ? 0 : 1;  // 1 => edge_index is int64
}

// P1: per-chunk LDS histogram over dst buckets. hist layout: [bin][chunk].
__global__ __launch_bounds__(256) void k_binhist(const void* __restrict__ ei,
                                                 int E, int CS, int B, int shift,
                                                 const int* __restrict__ meta,
                                                 int* __restrict__ hist, int C) {
  __shared__ int lh[256];
  int c = blockIdx.x;
  for (int i = threadIdx.x; i < B; i += 256) lh[i] = 0;
  __syncthreads();
  int e0 = c * CS, e1 = min(E, e0 + CS);
  bool is64 = meta[0] != 0;
  for (int e = e0 + threadIdx.x; e < e1; e += 256) {
    int d = is64 ? (int)((const long long*)ei)[(long)E + e]
                 : ((const int*)ei)[(long)E + e];
    atomicAdd(&lh[d >> shift], 1);
  }
  __syncthreads();
  for (int b = threadIdx.x; b < B; b += 256) hist[(long)b * C + c] = lh[b];
}

// P3: re-read edges, write (src,dst) pairs into reserved per-(chunk,bin)
// ranges. LDS cursors only -> zero global atomics.
__global__ __launch_bounds__(256) void k_binscatter(const void* __restrict__ ei,
                                                    int E, int CS, int B, int shift,
                                                    const int* __restrict__ meta,
                                                    const int* __restrict__ scan,
                                                    int C, int2* __restrict__ pairs) {
  __shared__ int cur[256];
  int c = blockIdx.x;
  for (int b = threadIdx.x; b < B; b += 256) cur[b] = scan[(long)b * C + c];
  __syncthreads();
  int e0 = c * CS, e1 = min(E, e0 + CS);
  bool is64 = meta[0] != 0;
  for (int e = e0 + threadIdx.x; e < e1; e += 256) {
    int s, d;
    if (is64) {
      const long long* p = (const long long*)ei;
      s = (int)p[e]; d = (int)p[(long)E + e];
    } else {
      const int* p = (const int*)ei;
      s = p[e]; d = p[(long)E + e];
    }
    int pos = atomicAdd(&cur[d >> shift], 1);
    pairs[pos] = make_int2(s, d);
  }
}

// P4a (fused): per-bucket degree hist -> cnt, dis=rsqrt(cnt+1), and
// rs = bucket_edge_base + LDS exclusive scan of degrees. Replaces the old
// k_bucketcnt + k_dis + 3-kernel global scan.
__global__ __launch_bounds__(256) void k_bucketprep(const int2* __restrict__ pairs,
                                                    const int* __restrict__ scan,
                                                    int C, int shift, int N,
                                                    int* __restrict__ cnt,
                                                    float* __restrict__ dis,
                                                    int* __restrict__ rs) {
  __shared__ int h[1024];
  __shared__ int sm[256];
  int bin = blockIdx.x;
  int base = bin << shift;
  int nn = min(N - base, 1 << shift);
  int t = threadIdx.x;
  for (int i = t; i < 1024; i += 256) h[i] = 0;
  __syncthreads();
  int p0 = scan[(long)bin * C];
  int p1 = scan[(long)(bin + 1) * C];  // sentinel row gives E for last bucket
  for (int i = p0 + t; i < p1; i += 256)
    atomicAdd(&h[pairs[i].y - base], 1);
  __syncthreads();
  // 4 elements per thread; block exclusive scan over the 256 partials.
  int v0 = h[4 * t], v1 = h[4 * t + 1], v2 = h[4 * t + 2], v3 = h[4 * t + 3];
  int s = v0 + v1 + v2 + v3;
  sm[t] = s;
  __syncthreads();
  for (int off = 1; off < 256; off <<= 1) {
    int x = (t >= off) ? sm[t - off] : 0;
    __syncthreads();
    sm[t] += x;
    __syncthreads();
  }
  int run = p0 + sm[t] - s;
  int r0 = run, r1 = run + v0, r2 = r1 + v1, r3 = r2 + v2;
  for (int k = 0; k < 4; ++k) {
    int i = 4 * t + k;
    if (i < nn) {
      int d = (k == 0) ? v0 : (k == 1) ? v1 : (k == 2) ? v2 : v3;
      int r = (k == 0) ? r0 : (k == 1) ? r1 : (k == 2) ? r2 : r3;
      cnt[base + i] = d;
      dis[base + i] = rsqrtf((float)d + 1.0f);
      rs[base + i] = r;
    }
  }
}

// P4b: per-bucket scatter into final CSR; LDS cursors seeded from rs.
__global__ __launch_bounds__(256) void k_bucketscatter(const int2* __restrict__ pairs,
                                                       const int* __restrict__ scan,
                                                       int C, int shift, int N,
                                                       const int* __restrict__ rs,
                                                       int* __restrict__ csr) {
  __shared__ int cur[1024];
  int bin = blockIdx.x;
  int base = bin << shift;
  int nn = min(N - base, 1 << shift);
  for (int i = threadIdx.x; i < nn; i += 256) cur[i] = rs[base + i];
  __syncthreads();
  int p0 = scan[(long)bin * C];
  int p1 = scan[(long)(bin + 1) * C];
  for (int i = p0 + threadIdx.x; i < p1; i += 256) {
    int2 pr = pairs[i];
    int pos = atomicAdd(&cur[pr.y - base], 1);
    csr[pos] = pr.x;
  }
}

__global__ __launch_bounds__(1024) void k_scan1(const int* __restrict__ cnt,
                                                int* __restrict__ bsums, int n) {
  __shared__ int sm[1024];
  int t = threadIdx.x;
  long i = (long)blockIdx.x * 1024 + t;
  sm[t] = (i < n) ? cnt[i] : 0;
  __syncthreads();
  for (int s = 512; s > 0; s >>= 1) {
    if (t < s) sm[t] += sm[t + s];
    __syncthreads();
  }
  if (t == 0) bsums[blockIdx.x] = sm[0];
}

__global__ void k_scan2(int* __restrict__ bsums, int nb) {
  __shared__ int sm[128];
  int t = threadIdx.x;
  int v = (t < nb) ? bsums[t] : 0;
  sm[t] = v;
  __syncthreads();
  for (int off = 1; off < 128; off <<= 1) {
    int x = (t >= off) ? sm[t - off] : 0;
    __syncthreads();
    sm[t] += x;
    __syncthreads();
  }
  if (t < nb) bsums[t] = sm[t] - v;  // exclusive
}

// exclusive scan -> out (may alias in); optional sentinel out[n] = total.
__global__ __launch_bounds__(1024) void k_scan3s(const int* __restrict__ in,
                                                 const int* __restrict__ bsums,
                                                 int* __restrict__ out, int n,
                                                 int sentinel) {
  __shared__ int sm[1024];
  int t = threadIdx.x;
  long i = (long)blockIdx.x * 1024 + t;
  int v = (i < n) ? in[i] : 0;
  sm[t] = v;
  __syncthreads();
  for (int off = 1; off < 1024; off <<= 1) {
    int x = (t >= off) ? sm[t - off] : 0;
    __syncthreads();
    sm[t] += x;
    __syncthreads();
  }
  int excl = sm[t] - v + bsums[blockIdx.x];
  if (i < n) out[i] = excl;
  if (sentinel && i == n - 1) out[n] = excl + v;
}

// C[n, M] = act(A[n, K] @ W[K, M] (+ bias)); W row-major [K][M], staged in LDS.
// K-loop pinned to no-unroll + manual next-k prefetch: 32 live A regs, no spill.
// OBF16: write output as bf16 (RNE) instead of fp32.
template <int K, int M, bool BIAS, int ACT, bool OBF16>
__global__ __launch_bounds__(256) void k_gemm(const float* __restrict__ A,
                                              const float* __restrict__ W,
                                              const float* __restrict__ bias,
                                              void* __restrict__ Cout, int nrows) {
  constexpr int CP = 4;
  constexpr int TPR = M / CP;        // threads per row
  constexpr int RG = 256 / TPR;      // row-groups per block
  constexpr int RP = 4;              // rows per thread
  constexpr int RT = RG * RP;        // rows per block
  __shared__ __align__(16) float sW[K * M];
  __shared__ __align__(16) float sB[BIAS ? M : 4];

  for (int i = threadIdx.x; i < K * M / 4; i += 256)
    ((float4*)sW)[i] = ((const float4*)W)[i];
  if (BIAS)
    for (int i = threadIdx.x; i < M; i += 256) sB[i] = bias[i];
  __syncthreads();

  const int cg = threadIdx.x % TPR;
  const int rg = threadIdx.x / TPR;
  const long row0 = (long)blockIdx.x * RT + rg;

  const float4* Ap[RP];
  bool valid[RP];
#pragma unroll
  for (int r = 0; r < RP; ++r) {
    long row = row0 + (long)r * RG;
    valid[r] = (row < nrows);
    Ap[r] = (const float4*)(A + (valid[r] ? row : 0) * K);
  }

  float acc[RP][CP] = {};
  float4 a[RP];
#pragma unroll
  for (int r = 0; r < RP; ++r)
    a[r] = valid[r] ? Ap[r][0] : make_float4(0.f, 0.f, 0.f, 0.f);

#pragma unroll 1
  for (int k0 = 0; k0 < K - 4; k0 += 4) {
    float4 an[RP];
#pragma unroll
    for (int r = 0; r < RP; ++r)
      an[r] = valid[r] ? Ap[r][k0 / 4 + 1] : make_float4(0.f, 0.f, 0.f, 0.f);
#pragma unroll
    for (int j = 0; j < 4; ++j) {
      float4 w = ((const float4*)(sW + (k0 + j) * M))[cg];
#pragma unroll
      for (int r = 0; r < RP; ++r) {
        float av = (j == 0) ? a[r].x : (j == 1) ? a[r].y : (j == 2) ? a[r].z : a[r].w;
        acc[r][0] += av * w.x;
        acc[r][1] += av * w.y;
        acc[r][2] += av * w.z;
        acc[r][3] += av * w.w;
      }
    }
#pragma unroll
    for (int r = 0; r < RP; ++r) a[r] = an[r];
  }
  {  // last k-step
    const int k0 = K - 4;
#pragma unroll
    for (int j = 0; j < 4; ++j) {
      float4 w = ((const float4*)(sW + (k0 + j) * M))[cg];
#pragma unroll
      for (int r = 0; r < RP; ++r) {
        float av = (j == 0) ? a[r].x : (j == 1) ? a[r].y : (j == 2) ? a[r].z : a[r].w;
        acc[r][0] += av * w.x;
        acc[r][1] += av * w.y;
        acc[r][2] += av * w.z;
        acc[r][3] += av * w.w;
      }
    }
  }

#pragma unroll
  for (int r = 0; r < RP; ++r) {
    long row = row0 + (long)r * RG;
    if (row >= nrows) continue;
    float4 o = make_float4(acc[r][0], acc[r][1], acc[r][2], acc[r][3]);
    if (BIAS) {
      float4 bb = ((const float4*)sB)[cg];
      o.x += bb.x; o.y += bb.y; o.z += bb.z; o.w += bb.w;
    }
    if (ACT == 1) {
      o.x = fmaxf(o.x, 0.f); o.y = fmaxf(o.y, 0.f);
      o.z = fmaxf(o.z, 0.f); o.w = fmaxf(o.w, 0.f);
    }
    if (OBF16) {
      __hip_bfloat16 b0 = __float2bfloat16(o.x);
      __hip_bfloat16 b1 = __float2bfloat16(o.y);
      __hip_bfloat16 b2 = __float2bfloat16(o.z);
      __hip_bfloat16 b3 = __float2bfloat16(o.w);
      ushort4 pk;
      pk.x = *(unsigned short*)&b0;
      pk.y = *(unsigned short*)&b1;
      pk.z = *(unsigned short*)&b2;
      pk.w = *(unsigned short*)&b3;
      ((ushort4*)((__hip_bfloat16*)Cout + row * M))[cg] = pk;
    } else {
      ((float4*)((float*)Cout + row * M))[cg] = o;
    }
  }
}

// Packed bf16x2 unpack helpers (bf16->f32 is a pure bit shift).
__device__ __forceinline__ float bf_lo(unsigned u) {
  return __uint_as_float(u << 16);
}
__device__ __forceinline__ float bf_hi(unsigned u) {
  return __uint_as_float(u & 0xffff0000u);
}

// Pull aggregation, D=64 bf16: 32 lanes per node (2 feats/lane), 2 nodes/wave.
// hw viewed as uint[n][32].
__global__ __launch_bounds__(256) void k_agg64p(const unsigned* __restrict__ hw,
                                                const int* __restrict__ csr,
                                                const int* __restrict__ rs,
                                                const int* __restrict__ cnt,
                                                const float* __restrict__ dis,
                                                const float* __restrict__ b,
                                                float* __restrict__ out, int n,
                                                int relu) {
  unsigned node = blockIdx.x * 8u + (threadIdx.x >> 5);
  if (node >= (unsigned)n) return;
  unsigned f2 = threadIdx.x & 31;
  float dsn = dis[node];
  unsigned su = hw[node * 32u + f2];
  float a0 = bf_lo(su) * dsn * dsn;  // self-loop
  float a1 = bf_hi(su) * dsn * dsn;
  int start = rs[node], deg = cnt[node];
  int e = 0;
  for (; e + 3 < deg; e += 4) {
    unsigned s0 = (unsigned)csr[start + e];
    unsigned s1 = (unsigned)csr[start + e + 1];
    unsigned s2 = (unsigned)csr[start + e + 2];
    unsigned s3 = (unsigned)csr[start + e + 3];
    float w0 = dis[s0] * dsn, w1 = dis[s1] * dsn;
    float w2 = dis[s2] * dsn, w3 = dis[s3] * dsn;
    unsigned u0 = hw[s0 * 32u + f2];
    unsigned u1 = hw[s1 * 32u + f2];
    unsigned u2 = hw[s2 * 32u + f2];
    unsigned u3 = hw[s3 * 32u + f2];
    a0 += bf_lo(u0) * w0 + bf_lo(u1) * w1 + bf_lo(u2) * w2 + bf_lo(u3) * w3;
    a1 += bf_hi(u0) * w0 + bf_hi(u1) * w1 + bf_hi(u2) * w2 + bf_hi(u3) * w3;
  }
  for (; e < deg; ++e) {
    unsigned s0 = (unsigned)csr[start + e];
    float w0 = dis[s0] * dsn;
    unsigned u0 = hw[s0 * 32u + f2];
    a0 += bf_lo(u0) * w0;
    a1 += bf_hi(u0) * w0;
  }
  float2 bb = ((const float2*)b)[f2];
  float o0 = a0 + bb.x, o1 = a1 + bb.y;
  if (relu) { o0 = fmaxf(o0, 0.f); o1 = fmaxf(o1, 0.f); }
  ((float2*)(out + node * 64u))[f2] = make_float2(o0, o1);
}

// Pull aggregation, D=32 bf16: 16 lanes per node (2 feats/lane), 4 nodes/wave.
// hw viewed as uint[n][16].
__global__ __launch_bounds__(256) void k_agg32p(const unsigned* __restrict__ hw,
                                                const int* __restrict__ csr,
                                                const int* __restrict__ rs,
                                                const int* __restrict__ cnt,
                                                const float* __restrict__ dis,
                                                const float* __restrict__ b,
                                                float* __restrict__ out, int n) {
  unsigned node = blockIdx.x * 16u + (threadIdx.x >> 4);
  if (node >= (unsigned)n) return;
  unsigned f2 = threadIdx.x & 15;
  float dsn = dis[node];
  unsigned su = hw[node * 16u + f2];
  float a0 = bf_lo(su) * dsn * dsn;
  float a1 = bf_hi(su) * dsn * dsn;
  int start = rs[node], deg = cnt[node];
  int e = 0;
  for (; e + 3 < deg; e += 4) {
    unsigned s0 = (unsigned)csr[start + e];
    unsigned s1 = (unsigned)csr[start + e + 1];
    unsigned s2 = (unsigned)csr[start + e + 2];
    unsigned s3 = (unsigned)csr[start + e + 3];
    float w0 = dis[s0] * dsn, w1 = dis[s1] * dsn;
    float w2 = dis[s2] * dsn, w3 = dis[s3] * dsn;
    unsigned u0 = hw[s0 * 16u + f2];
    unsigned u1 = hw[s1 * 16u + f2];
    unsigned u2 = hw[s2 * 16u + f2];
    unsigned u3 = hw[s3 * 16u + f2];
    a0 += bf_lo(u0) * w0 + bf_lo(u1) * w1 + bf_lo(u2) * w2 + bf_lo(u3) * w3;
    a1 += bf_hi(u0) * w0 + bf_hi(u1) * w1 + bf_hi(u2) * w2 + bf_hi(u3) * w3;
  }
  for (; e < deg; ++e) {
    unsigned s0 = (unsigned)csr[start + e];
    float w0 = dis[s0] * dsn;
    unsigned u0 = hw[s0 * 16u + f2];
    a0 += bf_lo(u0) * w0;
    a1 += bf_hi(u0) * w0;
  }
  float2 bb = ((const float2*)b)[f2];
  ((float2*)(out + node * 32u))[f2] = make_float2(a0 + bb.x, a1 + bb.y);
}

// score = sigmoid(s[N,32] @ sW2[32] + sb2); 8 nodes per 256-thread block.
__global__ void k_score(const float* __restrict__ s, const float* __restrict__ sW2,
                        const float* __restrict__ sb2, float* __restrict__ out, int n) {
  int node = blockIdx.x * 8 + (threadIdx.x >> 5);
  int k = threadIdx.x & 31;
  if (node >= n) return;
  float v = s[(long)node * 32 + k] * sW2[k];
  for (int off = 16; off > 0; off >>= 1) v += __shfl_down(v, off, 32);
  if (k == 0) out[node] = 1.0f / (1.0f + expf(-(v + sb2[0])));
}

extern "C" void kernel_launch(void* const* d_in, const int* in_sizes, int n_in,
                              void* d_out, int out_size, void* d_ws, size_t ws_size,
                              hipStream_t stream) {
  const float* x   = (const float*)d_in[0];
  const void*  ei  = d_in[1];
  const float* W1  = (const float*)d_in[2];
  const float* b1  = (const float*)d_in[3];
  const float* W2  = (const float*)d_in[4];
  const float* b2  = (const float*)d_in[5];
  const float* rW1 = (const float*)d_in[6];
  const float* rb1 = (const float*)d_in[7];
  const float* rW2 = (const float*)d_in[8];
  const float* rb2 = (const float*)d_in[9];
  const float* sW1 = (const float*)d_in[10];
  const float* sb1 = (const float*)d_in[11];
  const float* sW2 = (const float*)d_in[12];
  const float* sb2 = (const float*)d_in[13];

  const int N = in_sizes[0] / 128;
  const int E = in_sizes[1] / 2;

  // bucket geometry: SPB = 1<<shift nodes per bucket, B buckets (<=256)
  int shift = 9;
  while ((((long)N + (1L << shift) - 1) >> shift) > 256) ++shift;
  const int B = (int)(((long)N + (1L << shift) - 1) >> shift);
  const int C = 512;                       // edge chunks
  const int CS = (E + C - 1) / C;          // edges per chunk
  const int L = B * C;

  // workspace layout (256B aligned chunks)
  char* w = (char*)d_ws;
  auto alloc = [&](size_t bytes) {
    char* p = w;
    w += (bytes + 255) & ~(size_t)255;
    return p;
  };
  int*   meta   = (int*)alloc(64);
  int*   cnt    = (int*)alloc((size_t)N * 4);
  int*   rs     = (int*)alloc((size_t)N * 4);
  float* dis    = (float*)alloc((size_t)N * 4);
  int*   bsumsL = (int*)alloc(1024);
  int*   bscan  = (int*)alloc(((size_t)L + 1) * 4);
  int*   csr    = (int*)alloc((size_t)E * 4);
  // union buffer: pairs (E*8B) -> later tbuf (N*64*4B fp32) / sbuf
  size_t uni = (size_t)E * 8 > (size_t)N * 256 ? (size_t)E * 8 : (size_t)N * 256;
  char*  u      = alloc(uni);
  int2*  pairs  = (int2*)u;
  float* tbuf   = (float*)u;                 // recon intermediate [N,64] fp32
  float* sbuf   = (float*)u;                 // scorer intermediate [N,32] fp32
  unsigned* hw1 = (unsigned*)alloc((size_t)N * 64 * 2);  // bf16 [N][64]
  float* h1     = (float*)alloc((size_t)N * 64 * 4);
  unsigned* hw2 = (unsigned*)alloc((size_t)N * 32 * 2);  // bf16 [N][32]

  float* h_out = (float*)d_out;                 // [N,32]
  float* x_rec = h_out + (long)N * 32;          // [N,128]
  float* score = x_rec + (long)N * 128;         // [N,1]

  // ---- CSR build (atomic-free two-level counting sort) ----
  k_detect<<<1, 256, 0, stream>>>((const unsigned int*)ei, E < 4096 ? E : 4096, meta);
  k_binhist<<<C, 256, 0, stream>>>(ei, E, CS, B, shift, meta, bscan, C);
  int nbL = (L + 1023) / 1024;
  k_scan1<<<nbL, 1024, 0, stream>>>(bscan, bsumsL, L);
  k_scan2<<<1, 128, 0, stream>>>(bsumsL, nbL);
  k_scan3s<<<nbL, 1024, 0, stream>>>(bscan, bsumsL, bscan, L, 1);  // in-place + sentinel
  k_binscatter<<<C, 256, 0, stream>>>(ei, E, CS, B, shift, meta, bscan, C, pairs);
  k_bucketprep<<<B, 256, 0, stream>>>(pairs, bscan, C, shift, N, cnt, dis, rs);
  k_bucketscatter<<<B, 256, 0, stream>>>(pairs, bscan, C, shift, N, rs, csr);

  // ---- layer 1: hw1 = bf16(x @ W1) ; h1 = relu(agg + b1) ----
  k_gemm<128, 64, false, 0, true><<<(N + 63) / 64, 256, 0, stream>>>(x, W1, nullptr, hw1, N);
  k_agg64p<<<(N + 7) / 8, 256, 0, stream>>>(hw1, csr, rs, cnt, dis, b1, h1, N, 1);

  // ---- layer 2: hw2 = bf16(h1 @ W2) ; h = agg + b2 -> d_out ----
  k_gemm<64, 32, false, 0, true><<<(N + 127) / 128, 256, 0, stream>>>(h1, W2, nullptr, hw2, N);
  k_agg32p<<<(N + 15) / 16, 256, 0, stream>>>(hw2, csr, rs, cnt, dis, b2, h_out, N);

  // ---- reconstruction MLP: t = relu(h@rW1+rb1) ; x_rec = t@rW2+rb2 ----
  k_gemm<32, 64, true, 1, false><<<(N + 63) / 64, 256, 0, stream>>>(h_out, rW1, rb1, tbuf, N);
  k_gemm<64, 128, true, 0, false><<<(N + 31) / 32, 256, 0, stream>>>(tbuf, rW2, rb2, x_rec, N);

  // ---- scorer MLP: s = relu(h@sW1+sb1) ; score = sigmoid(s@sW2+sb2) ----
  k_gemm<32, 32, true, 1, false><<<(N + 127) / 128, 256, 0, stream>>>(h_out, sW1, sb1, sbuf, N);
  k_score<<<(N + 7) / 8, 256, 0, stream>>>(sbuf, sW2, sb2, score, N);
}